// Round 2
// baseline (2210.003 us; speedup 1.0000x reference)
//
#include <hip/hip_runtime.h>
#include <math.h>

#define T_ 64
#define N_ 40
#define D_ 4
#define H_ 256
#define R_ 64
#define E_ 1560
#define TE_ (T_*E_)   // 99840
#define TN_ (T_*N_)   // 2560

__device__ __forceinline__ float elu_f(float x){ return x > 0.f ? x : (__expf(x) - 1.f); }
__device__ __forceinline__ float sig_f(float x){ return 1.f/(1.f+__expf(-x)); }
__device__ __forceinline__ float tanh_f(float x){ return 2.f/(1.f+__expf(-2.f*x)) - 1.f; }
__device__ __forceinline__ float dot4(float4 a, float4 b){ return a.x*b.x + a.y*b.y + a.z*b.z + a.w*b.w; }

// bf16 <-> fp32 (bf16 kept as unsigned short; RNE rounding on store)
__device__ __forceinline__ float bf2f(unsigned short u){ return __uint_as_float(((unsigned int)u) << 16); }
__device__ __forceinline__ unsigned short f2bf(float f){
    unsigned int u = __float_as_uint(f);
    u += 0x7FFFu + ((u >> 16) & 1u);
    return (unsigned short)(u >> 16);
}
__device__ __forceinline__ float4 ld4f(const float* p){ return *(const float4*)p; }
__device__ __forceinline__ float4 ld4f(const unsigned short* p){
    ushort4 v = *(const ushort4*)p;
    return make_float4(bf2f(v.x), bf2f(v.y), bf2f(v.z), bf2f(v.w));
}
__device__ __forceinline__ void st4f(float* p, float4 v){ *(float4*)p = v; }
__device__ __forceinline__ void st4f(unsigned short* p, float4 v){
    ushort4 o; o.x = f2bf(v.x); o.y = f2bf(v.y); o.z = f2bf(v.z); o.w = f2bf(v.w);
    *(ushort4*)p = o;
}

// ---------------------------------------------------------------------------
// mlp1: x [TN,4] -> elu(elu(x W1^T + b1) W2^T + b2) -> h [TN,256] (fp32)
// ---------------------------------------------------------------------------
__global__ __launch_bounds__(256)
void mlp1_kernel(const float* __restrict__ x,
                 const float* __restrict__ W1, const float* __restrict__ b1,
                 const float* __restrict__ W2, const float* __restrict__ b2,
                 float* __restrict__ hout)
{
    __shared__ float xs[8][4];
    __shared__ float h1[8][256];
    const int tid = threadIdx.x;
    const int r0  = blockIdx.x * 8;

    if (tid < 32) xs[tid >> 2][tid & 3] = x[r0 * 4 + tid];
    __syncthreads();

    const float4 w1 = *(const float4*)&W1[tid * 4];
    const float bb1 = b1[tid];
    #pragma unroll
    for (int row = 0; row < 8; ++row) {
        float v = bb1 + xs[row][0]*w1.x + xs[row][1]*w1.y + xs[row][2]*w1.z + xs[row][3]*w1.w;
        h1[row][tid] = elu_f(v);
    }
    __syncthreads();

    float acc[8];
    const float bb2 = b2[tid];
    #pragma unroll
    for (int row = 0; row < 8; ++row) acc[row] = bb2;
    const float* w2row = W2 + (size_t)tid * 256;
    for (int k4 = 0; k4 < 64; ++k4) {
        const float4 w = *(const float4*)&w2row[k4 * 4];
        #pragma unroll
        for (int row = 0; row < 8; ++row) {
            const float4 hh = *(const float4*)&h1[row][k4 * 4];
            acc[row] += dot4(hh, w);
        }
    }
    #pragma unroll
    for (int row = 0; row < 8; ++row)
        hout[(size_t)(r0 + row) * 256 + tid] = elu_f(acc[row]);
}

// ---------------------------------------------------------------------------
// Tiled NT GEMM: C[M,256] = act(A[M,K] @ W[256,K]^T + b1 (+ b2))
// MODE 0: plain A. MODE 1: row = concat(A[t,send[e]], A2[t,recv[e]]), K=512.
// MODE 2: row = concat(A[t,send], A2[t,recv], A3[t,e]), K=768.
// TA: element type of A/A2 (float or bf16-as-ushort). TA3: of A3. TC: output.
// 64x64 tile, BK=16, 256 threads, 4x4 register tile.
// ---------------------------------------------------------------------------
template<int MODE, bool DOELU, typename TA, typename TA3, typename TC>
__global__ __launch_bounds__(256)
void gemm_nt(const TA* __restrict__ A, const TA* __restrict__ A2,
             const TA3* __restrict__ A3,
             const float* __restrict__ W,
             const float* __restrict__ bias1, const float* __restrict__ bias2,
             const int* __restrict__ send, const int* __restrict__ recv,
             TC* __restrict__ C, int M, int Kdim)
{
    __shared__ float As[16][64];
    __shared__ float Ws[16][64];

    const int tid = threadIdx.x;
    const int am  = tid >> 2;           // 0..63 : row within tile (loader)
    const int ak  = (tid & 3) * 4;      // 0,4,8,12 : k within BK (loader)
    const int gm  = blockIdx.x * 64 + am;

    const TA* aptr0 = nullptr; const TA* aptr1 = nullptr; const TA3* aptr2 = nullptr;
    if (MODE == 0) {
        aptr0 = A + (size_t)gm * Kdim;
    } else {
        const int t = gm / E_;
        const int e = gm - t * E_;
        aptr0 = A  + ((size_t)(t * N_ + send[e])) * H_;
        aptr1 = A2 + ((size_t)(t * N_ + recv[e])) * H_;
        if (MODE == 2) aptr2 = A3 + (size_t)gm * H_;
    }
    const float* wptr = W + (size_t)(blockIdx.y * 64 + am) * Kdim;

    const int tx = tid & 15, ty = tid >> 4;
    float acc[4][4] = {};

    for (int k0 = 0; k0 < Kdim; k0 += 16) {
        const int kk = k0 + ak;
        float4 a4;
        if (MODE == 0) {
            a4 = ld4f(aptr0 + kk);
        } else if (MODE == 1) {
            a4 = (kk < 256) ? ld4f(aptr0 + kk)
                            : ld4f(aptr1 + kk - 256);
        } else {
            a4 = (kk < 256) ? ld4f(aptr0 + kk)
               : (kk < 512) ? ld4f(aptr1 + kk - 256)
                            : ld4f(aptr2 + kk - 512);
        }
        const float4 w4 = *(const float4*)(wptr + k0 + (tid & 3) * 4);

        __syncthreads();
        As[ak+0][am] = a4.x; As[ak+1][am] = a4.y; As[ak+2][am] = a4.z; As[ak+3][am] = a4.w;
        const int wk = (tid & 3) * 4;
        Ws[wk+0][am] = w4.x; Ws[wk+1][am] = w4.y; Ws[wk+2][am] = w4.z; Ws[wk+3][am] = w4.w;
        __syncthreads();

        #pragma unroll
        for (int kq = 0; kq < 16; ++kq) {
            const float4 av = *(const float4*)&As[kq][ty * 4];
            const float4 wv = *(const float4*)&Ws[kq][tx * 4];
            const float a_[4] = {av.x, av.y, av.z, av.w};
            const float w_[4] = {wv.x, wv.y, wv.z, wv.w};
            #pragma unroll
            for (int i = 0; i < 4; ++i)
                #pragma unroll
                for (int j = 0; j < 4; ++j)
                    acc[i][j] += a_[i] * w_[j];
        }
    }

    const int gn = blockIdx.y * 64 + tx * 4;
    float4 bb = *(const float4*)&bias1[gn];
    if (bias2) {
        const float4 b2v = *(const float4*)&bias2[gn];
        bb.x += b2v.x; bb.y += b2v.y; bb.z += b2v.z; bb.w += b2v.w;
    }
    #pragma unroll
    for (int i = 0; i < 4; ++i) {
        const int row = blockIdx.x * 64 + ty * 4 + i;
        float4 o;
        o.x = acc[i][0] + bb.x; o.y = acc[i][1] + bb.y;
        o.z = acc[i][2] + bb.z; o.w = acc[i][3] + bb.w;
        if (DOELU) { o.x = elu_f(o.x); o.y = elu_f(o.y); o.z = elu_f(o.z); o.w = elu_f(o.w); }
        st4f(C + (size_t)row * 256 + gn, o);
    }
}

// ---------------------------------------------------------------------------
// edge2node scatter-add as deterministic gather: one block per (t,j).
// ---------------------------------------------------------------------------
__global__ __launch_bounds__(256)
void aggregate_kernel(const unsigned short* __restrict__ eSkip, const int* __restrict__ recv,
                      float* __restrict__ nAgg)
{
    const int t = blockIdx.x / N_;
    const int j = blockIdx.x - t * N_;
    const int c = threadIdx.x;
    const unsigned short* basep = eSkip + (size_t)t * E_ * H_;
    float acc = 0.f;
    for (int e = 0; e < E_; ++e) {
        if (recv[e] == j) acc += bf2f(basep[(size_t)e * H_ + c]);
    }
    nAgg[(size_t)blockIdx.x * H_ + c] = acc;
}

// ---------------------------------------------------------------------------
// LSTM recurrence over T. Gates G[T,E,256] (bf16) precomputed = e4@Wih^T+bih+bhh.
// Each block: 8 edges, one direction. Thread tid owns gate col tid; Whh row in
// 64 VGPRs; h-state in LDS; c-state in registers.
// ---------------------------------------------------------------------------
__global__ __launch_bounds__(256)
void lstm_kernel(const unsigned short* __restrict__ Gf, const unsigned short* __restrict__ Gr,
                 const float* __restrict__ fWhh, const float* __restrict__ rWhh,
                 float* __restrict__ hsF, float* __restrict__ hsR)
{
    const int NB = E_ / 8;   // 195 blocks per direction
    const int bid = blockIdx.x;
    const bool revd = (bid >= NB);
    const int e0 = (revd ? bid - NB : bid) * 8;
    const unsigned short* G = revd ? Gr : Gf;
    const float* Whh        = revd ? rWhh : fWhh;
    float* hs               = revd ? hsR : hsF;
    const int tid = threadIdx.x;

    float4 w[16];
    #pragma unroll
    for (int q = 0; q < 16; ++q) w[q] = *(const float4*)(Whh + (size_t)tid * 64 + q * 4);

    __shared__ float h_s[8][64];
    __shared__ float g_s[8][256];

    const int le0 = tid >> 6;      // wave id 0..3
    const int r   = tid & 63;
    float c0 = 0.f, c1 = 0.f;
    h_s[le0][r] = 0.f;
    h_s[le0 + 4][r] = 0.f;
    __syncthreads();

    for (int s = 0; s < T_; ++s) {
        const int tt = revd ? (T_ - 1 - s) : s;
        const unsigned short* gRow = G + ((size_t)tt * E_ + e0) * 256;
        #pragma unroll
        for (int le = 0; le < 8; ++le) {
            float gv = bf2f(gRow[(size_t)le * 256 + tid]);
            const float4* hp = (const float4*)h_s[le];
            #pragma unroll
            for (int q = 0; q < 16; ++q) {
                const float4 h4 = hp[q];
                gv += h4.x*w[q].x + h4.y*w[q].y + h4.z*w[q].z + h4.w*w[q].w;
            }
            g_s[le][tid] = gv;
        }
        __syncthreads();
        float* hrow = hs + ((size_t)tt * E_ + e0) * 64;
        {
            const int le = le0;
            const float gi = g_s[le][r], gf = g_s[le][64 + r];
            const float gg = g_s[le][128 + r], go = g_s[le][192 + r];
            const float cc = sig_f(gf) * c0 + sig_f(gi) * tanh_f(gg);
            c0 = cc;
            const float hh = sig_f(go) * tanh_f(cc);
            h_s[le][r] = hh;
            hrow[(size_t)le * 64 + r] = hh;
        }
        {
            const int le = le0 + 4;
            const float gi = g_s[le][r], gf = g_s[le][64 + r];
            const float gg = g_s[le][128 + r], go = g_s[le][192 + r];
            const float cc = sig_f(gf) * c1 + sig_f(gi) * tanh_f(gg);
            c1 = cc;
            const float hh = sig_f(go) * tanh_f(cc);
            h_s[le][r] = hh;
            hrow[(size_t)le * 64 + r] = hh;
        }
        __syncthreads();
    }
}

// ---------------------------------------------------------------------------
// prior = fwd_h @ priW^T + prib ; enc = [fwd_h, rev_h] @ encW^T + encb
// ---------------------------------------------------------------------------
__global__ __launch_bounds__(256)
void out_kernel(const float* __restrict__ hsF, const float* __restrict__ hsR,
                const float* __restrict__ priW, const float* __restrict__ prib,
                const float* __restrict__ encW, const float* __restrict__ encb,
                float* __restrict__ out)
{
    const int idx = blockIdx.x * 256 + threadIdx.x;  // grid sized exactly TE_
    const float* f = hsF + (size_t)idx * 64;
    const float* r = hsR + (size_t)idx * 64;
    float p0 = prib[0], p1 = prib[1], q0 = encb[0], q1 = encb[1];
    #pragma unroll
    for (int k4 = 0; k4 < 16; ++k4) {
        const float4 fv = *(const float4*)(f + k4 * 4);
        const float4 rv = *(const float4*)(r + k4 * 4);
        p0 += dot4(fv, *(const float4*)(priW + k4 * 4));
        p1 += dot4(fv, *(const float4*)(priW + 64 + k4 * 4));
        q0 += dot4(fv, *(const float4*)(encW + k4 * 4))
            + dot4(rv, *(const float4*)(encW + 64 + k4 * 4));
        q1 += dot4(fv, *(const float4*)(encW + 128 + k4 * 4))
            + dot4(rv, *(const float4*)(encW + 192 + k4 * 4));
    }
    float4 o; o.x = p0; o.y = p1; o.z = q0; o.w = q1;
    *(float4*)(out + (size_t)idx * 4) = o;
}

// ---------------------------------------------------------------------------
extern "C" void kernel_launch(void* const* d_in, const int* in_sizes, int n_in,
                              void* d_out, int out_size, void* d_ws, size_t ws_size,
                              hipStream_t stream)
{
    const float* x    = (const float*)d_in[0];
    const int*   send = (const int*)d_in[2];
    const int*   recv = (const int*)d_in[3];
    const float* m1W1 = (const float*)d_in[4];  const float* m1b1 = (const float*)d_in[5];
    const float* m1W2 = (const float*)d_in[6];  const float* m1b2 = (const float*)d_in[7];
    const float* m2W1 = (const float*)d_in[8];  const float* m2b1 = (const float*)d_in[9];
    const float* m2W2 = (const float*)d_in[10]; const float* m2b2 = (const float*)d_in[11];
    const float* m3W1 = (const float*)d_in[12]; const float* m3b1 = (const float*)d_in[13];
    const float* m3W2 = (const float*)d_in[14]; const float* m3b2 = (const float*)d_in[15];
    const float* m4W1 = (const float*)d_in[16]; const float* m4b1 = (const float*)d_in[17];
    const float* m4W2 = (const float*)d_in[18]; const float* m4b2 = (const float*)d_in[19];
    const float* fWih = (const float*)d_in[20]; const float* fWhh = (const float*)d_in[21];
    const float* fbih = (const float*)d_in[22]; const float* fbhh = (const float*)d_in[23];
    const float* rWih = (const float*)d_in[24]; const float* rWhh = (const float*)d_in[25];
    const float* rbih = (const float*)d_in[26]; const float* rbhh = (const float*)d_in[27];
    const float* encW = (const float*)d_in[28]; const float* encb = (const float*)d_in[29];
    const float* priW = (const float*)d_in[30]; const float* prib = (const float*)d_in[31];

    // --- workspace layout (163,840,000 bytes total) ---
    // fp32 node buffers: 4 x [TN,256]; bf16 edge buffers: 3 x [TE,256];
    // hsF/hsR (fp32 [TE,64] each) alias bufC16 (e4 dead once gates are built).
    const size_t SZN = (size_t)TN_ * H_;
    const size_t SZE16 = (size_t)TE_ * H_;
    const size_t needed = 4 * SZN * sizeof(float) + 3 * SZE16 * sizeof(unsigned short);
    if (ws_size < needed) return;   // diagnostic: zero output == ws too small

    float* h_nodes = (float*)d_ws;
    float* n_agg   = h_nodes + SZN;
    float* m3t     = n_agg   + SZN;
    float* n3      = m3t     + SZN;
    unsigned short* bufA16 = (unsigned short*)(n3 + SZN);
    unsigned short* bufB16 = bufA16 + SZE16;
    unsigned short* bufC16 = bufB16 + SZE16;
    float* hsF = (float*)bufC16;                 // alias: TE*64 fp32
    float* hsR = hsF + (size_t)TE_ * R_;         // alias: TE*64 fp32 (exactly fills bufC16)

    const dim3 gE(TE_ / 64, 4), gN(TN_ / 64, 4);
    typedef unsigned short us;

    // 1. node MLP (fp32)
    mlp1_kernel<<<TN_ / 8, 256, 0, stream>>>(x, m1W1, m1b1, m1W2, m1b2, h_nodes);
    // 2. mlp2 on gathered edge features -> skip (bf16)
    gemm_nt<1, true, float, us, us><<<gE, 256, 0, stream>>>(h_nodes, h_nodes, (const us*)nullptr, m2W1, m2b1, nullptr, send, recv, bufA16, TE_, 512);
    gemm_nt<0, true, us, us, us><<<gE, 256, 0, stream>>>(bufA16, nullptr, nullptr, m2W2, m2b2, nullptr, send, recv, bufB16, TE_, 256);
    // 3. edge->node aggregate (fp32), mlp3 (fp32)
    aggregate_kernel<<<TN_, 256, 0, stream>>>(bufB16, recv, n_agg);
    gemm_nt<0, true, float, us, float><<<gN, 256, 0, stream>>>(n_agg, nullptr, (const us*)nullptr, m3W1, m3b1, nullptr, send, recv, m3t, TN_, 256);
    gemm_nt<0, true, float, us, float><<<gN, 256, 0, stream>>>(m3t, nullptr, (const us*)nullptr, m3W2, m3b2, nullptr, send, recv, n3, TN_, 256);
    // 4. mlp4 on gathered (n_send, n_recv, skip) -> e4 (bf16)
    gemm_nt<2, true, float, us, us><<<gE, 256, 0, stream>>>(n3, n3, bufB16, m4W1, m4b1, nullptr, send, recv, bufA16, TE_, 768);
    gemm_nt<0, true, us, us, us><<<gE, 256, 0, stream>>>(bufA16, nullptr, nullptr, m4W2, m4b2, nullptr, send, recv, bufC16, TE_, 256);
    // 5. LSTM input pre-gates (bias = bih + bhh), bf16
    gemm_nt<0, false, us, us, us><<<gE, 256, 0, stream>>>(bufC16, nullptr, nullptr, fWih, fbih, fbhh, send, recv, bufA16, TE_, 256);
    gemm_nt<0, false, us, us, us><<<gE, 256, 0, stream>>>(bufC16, nullptr, nullptr, rWih, rbih, rbhh, send, recv, bufB16, TE_, 256);
    // 6. recurrence (fwd + rev in one launch); writes hs over dead e4 buffer
    lstm_kernel<<<2 * (E_ / 8), 256, 0, stream>>>(bufA16, bufB16, fWhh, rWhh, hsF, hsR);
    // 7. output projections
    out_kernel<<<TE_ / 256, 256, 0, stream>>>(hsF, hsR, priW, prib, encW, encb, (float*)d_out);
}

// Round 3
// 1165.266 us; speedup vs baseline: 1.8966x; 1.8966x over previous
//
#include <hip/hip_runtime.h>
#include <math.h>

#define T_ 64
#define N_ 40
#define D_ 4
#define H_ 256
#define R_ 64
#define E_ 1560
#define TE_ (T_*E_)   // 99840
#define TN_ (T_*N_)   // 2560

typedef unsigned short us;
typedef short short8 __attribute__((ext_vector_type(8)));
typedef float f32x4 __attribute__((ext_vector_type(4)));

__device__ __forceinline__ float elu_f(float x){ return x > 0.f ? x : (__expf(x) - 1.f); }
__device__ __forceinline__ float sig_f(float x){ return 1.f/(1.f+__expf(-x)); }
__device__ __forceinline__ float tanh_f(float x){ return 2.f/(1.f+__expf(-2.f*x)) - 1.f; }
__device__ __forceinline__ float dot4(float4 a, float4 b){ return a.x*b.x + a.y*b.y + a.z*b.z + a.w*b.w; }

__device__ __forceinline__ float bf2f(us u){ return __uint_as_float(((unsigned int)u) << 16); }
__device__ __forceinline__ us f2bf(float f){
    unsigned int u = __float_as_uint(f);
    u += 0x7FFFu + ((u >> 16) & 1u);
    return (us)(u >> 16);
}
__device__ __forceinline__ float4 ld4f(const float* p){ return *(const float4*)p; }
__device__ __forceinline__ float4 ld4f(const us* p){
    ushort4 v = *(const ushort4*)p;
    return make_float4(bf2f(v.x), bf2f(v.y), bf2f(v.z), bf2f(v.w));
}
__device__ __forceinline__ void st4f(float* p, float4 v){ *(float4*)p = v; }
__device__ __forceinline__ void st4f(us* p, float4 v){
    ushort4 o; o.x = f2bf(v.x); o.y = f2bf(v.y); o.z = f2bf(v.z); o.w = f2bf(v.w);
    *(ushort4*)p = o;
}

// async global->LDS, 16B per lane; lds dest must be wave-uniform (HW adds lane*16)
__device__ __forceinline__ void gld16(void* lds, const void* g){
    __builtin_amdgcn_global_load_lds((const __attribute__((address_space(1))) unsigned int*)g,
                                     (__attribute__((address_space(3))) unsigned int*)lds,
                                     16, 0, 0);
}

// ---------------------------------------------------------------------------
// weight split: W(fp32) -> hi = bf16(W), lo = bf16(W - hi). hi+lo ~ fp32.
// ---------------------------------------------------------------------------
__global__ __launch_bounds__(256)
void wsplit_kernel(const float* __restrict__ W, us* __restrict__ hi, us* __restrict__ lo, int n)
{
    const int i = blockIdx.x * 256 + threadIdx.x;
    if (i < n) {
        const float w = W[i];
        const us h = f2bf(w);
        hi[i] = h;
        lo[i] = f2bf(w - bf2f(h));
    }
}

// ---------------------------------------------------------------------------
// mlp1: x [TN,4] -> elu(elu(x W1^T + b1) W2^T + b2) -> h [TN,256] (bf16)
// ---------------------------------------------------------------------------
__global__ __launch_bounds__(256)
void mlp1_kernel(const float* __restrict__ x,
                 const float* __restrict__ W1, const float* __restrict__ b1,
                 const float* __restrict__ W2, const float* __restrict__ b2,
                 us* __restrict__ hout)
{
    __shared__ float xs[8][4];
    __shared__ float h1[8][256];
    const int tid = threadIdx.x;
    const int r0  = blockIdx.x * 8;

    if (tid < 32) xs[tid >> 2][tid & 3] = x[r0 * 4 + tid];
    __syncthreads();

    const float4 w1 = *(const float4*)&W1[tid * 4];
    const float bb1 = b1[tid];
    #pragma unroll
    for (int row = 0; row < 8; ++row) {
        float v = bb1 + xs[row][0]*w1.x + xs[row][1]*w1.y + xs[row][2]*w1.z + xs[row][3]*w1.w;
        h1[row][tid] = elu_f(v);
    }
    __syncthreads();

    float acc[8];
    const float bb2 = b2[tid];
    #pragma unroll
    for (int row = 0; row < 8; ++row) acc[row] = bb2;
    const float* w2row = W2 + (size_t)tid * 256;
    for (int k4 = 0; k4 < 64; ++k4) {
        const float4 w = *(const float4*)&w2row[k4 * 4];
        #pragma unroll
        for (int row = 0; row < 8; ++row) {
            const float4 hh = *(const float4*)&h1[row][k4 * 4];
            acc[row] += dot4(hh, w);
        }
    }
    #pragma unroll
    for (int row = 0; row < 8; ++row)
        hout[(size_t)(r0 + row) * 256 + tid] = f2bf(elu_f(acc[row]));
}

// ---------------------------------------------------------------------------
// MFMA NT GEMM: C[M,256](bf16) = act(A[M,K](bf16) @ (Whi+Wlo)[256,K]^T + b1(+b2))
// 128 edges x 128 features per block, BK=32, 4 waves, 16x16x32 bf16 MFMA.
// Operands swapped (W = MFMA-A / m-axis, edges = MFMA-B / n-axis) so the C/D
// reg-axis lands on feature columns -> packed ushort4 stores.
// LDS: per tile, 4 k-planes x 128 rows x 16B (lane-contiguous for global_load_lds;
// fragment ds_read_b128 is 2-way-bank-aliased only).
// MODE 0: plain rows. MODE 1: row = concat(A[t,send], A2[t,recv]) K=512.
// MODE 2: concat(A[t,send], A2[t,recv], A3[row]) K=768.
// ---------------------------------------------------------------------------
template<int MODE, bool DOELU>
__global__ __launch_bounds__(256)
void gemm_mfma(const us* __restrict__ A, const us* __restrict__ A2, const us* __restrict__ A3,
               const us* __restrict__ Whi, const us* __restrict__ Wlo,
               const float* __restrict__ bias1, const float* __restrict__ bias2,
               const int* __restrict__ send, const int* __restrict__ recv,
               us* __restrict__ C, int Kdim)
{
    __shared__ char smem[24576];
    char* ldsA  = smem;            // 8KB edge tile
    char* ldsWh = smem + 8192;     // 8KB W-hi tile
    char* ldsWl = smem + 16384;    // 8KB W-lo tile

    const int tid  = threadIdx.x;
    const int lane = tid & 63;
    const int w    = tid >> 6;     // wave 0..3; stages k-plane w
    const int ml   = lane & 15;
    const int q    = lane >> 4;
    const int bx   = blockIdx.x;   // edge tile (128 rows)
    const int by   = blockIdx.y;   // feature tile (128 cols)
    const int eh   = w >> 1;       // edge half owned by this wave
    const int fh   = w & 1;        // feature half

    // staging row pointers: lane stages rows (lane) and (lane+64)
    const int gr0 = bx * 128 + lane, gr1 = gr0 + 64;
    const us *pA0a=nullptr,*pA1a=nullptr,*pA2a=nullptr;
    const us *pA0b=nullptr,*pA1b=nullptr,*pA2b=nullptr;
    if (MODE == 0) {
        pA0a = A + (size_t)gr0 * Kdim;
        pA0b = A + (size_t)gr1 * Kdim;
    } else {
        const int t0 = gr0 / E_, e0 = gr0 - t0 * E_;
        const int t1 = gr1 / E_, e1 = gr1 - t1 * E_;
        pA0a = A  + ((size_t)(t0 * N_ + send[e0])) * H_;
        pA1a = A2 + ((size_t)(t0 * N_ + recv[e0])) * H_;
        pA0b = A  + ((size_t)(t1 * N_ + send[e1])) * H_;
        pA1b = A2 + ((size_t)(t1 * N_ + recv[e1])) * H_;
        if (MODE == 2) { pA2a = A3 + (size_t)gr0 * H_; pA2b = A3 + (size_t)gr1 * H_; }
    }
    const us* pWh0 = Whi + (size_t)(by * 128 + lane)      * Kdim;
    const us* pWh1 = Whi + (size_t)(by * 128 + 64 + lane) * Kdim;
    const us* pWl0 = Wlo + (size_t)(by * 128 + lane)      * Kdim;
    const us* pWl1 = Wlo + (size_t)(by * 128 + 64 + lane) * Kdim;

    f32x4 acc[4][4];
    #pragma unroll
    for (int i = 0; i < 4; ++i)
        #pragma unroll
        for (int j = 0; j < 4; ++j)
            acc[i][j] = (f32x4){0.f, 0.f, 0.f, 0.f};

    for (int k0 = 0; k0 < Kdim; k0 += 32) {
        __syncthreads();   // prior tile fully consumed before overwrite
        const int kk = k0 + w * 8;   // this wave's k-plane chunk
        const us *sa, *sb;
        if (MODE == 0) { sa = pA0a + kk; sb = pA0b + kk; }
        else if (MODE == 1) {
            sa = (kk < 256) ? pA0a + kk : pA1a + (kk - 256);
            sb = (kk < 256) ? pA0b + kk : pA1b + (kk - 256);
        } else {
            sa = (kk < 256) ? pA0a + kk : (kk < 512) ? pA1a + (kk - 256) : pA2a + (kk - 512);
            sb = (kk < 256) ? pA0b + kk : (kk < 512) ? pA1b + (kk - 256) : pA2b + (kk - 512);
        }
        gld16(ldsA  + w * 2048,        sa);
        gld16(ldsA  + w * 2048 + 1024, sb);
        gld16(ldsWh + w * 2048,        pWh0 + kk);
        gld16(ldsWh + w * 2048 + 1024, pWh1 + kk);
        gld16(ldsWl + w * 2048,        pWl0 + kk);
        gld16(ldsWl + w * 2048 + 1024, pWl1 + kk);
        __builtin_amdgcn_s_waitcnt(0x3F70);  // vmcnt(0) only
        __syncthreads();   // all planes landed

        short8 wh[4], wl[4], ef[4];
        #pragma unroll
        for (int mt = 0; mt < 4; ++mt) {
            const int fr = fh * 64 + mt * 16 + ml;
            wh[mt] = *(const short8*)(ldsWh + q * 2048 + fr * 16);
            wl[mt] = *(const short8*)(ldsWl + q * 2048 + fr * 16);
        }
        #pragma unroll
        for (int nt = 0; nt < 4; ++nt) {
            const int er = eh * 64 + nt * 16 + ml;
            ef[nt] = *(const short8*)(ldsA + q * 2048 + er * 16);
        }
        #pragma unroll
        for (int mt = 0; mt < 4; ++mt)
            #pragma unroll
            for (int nt = 0; nt < 4; ++nt) {
                acc[mt][nt] = __builtin_amdgcn_mfma_f32_16x16x32_bf16(wh[mt], ef[nt], acc[mt][nt], 0, 0, 0);
                acc[mt][nt] = __builtin_amdgcn_mfma_f32_16x16x32_bf16(wl[mt], ef[nt], acc[mt][nt], 0, 0, 0);
            }
    }

    // epilogue: lane holds cols (colb..colb+3) x rows (per nt); D: n-axis=edges on
    // lane&15, m-axis=features on quad*4+reg.
    #pragma unroll
    for (int mt = 0; mt < 4; ++mt) {
        const int colb = by * 128 + fh * 64 + mt * 16 + q * 4;
        float4 bb = *(const float4*)(bias1 + colb);
        if (bias2) {
            const float4 b2 = *(const float4*)(bias2 + colb);
            bb.x += b2.x; bb.y += b2.y; bb.z += b2.z; bb.w += b2.w;
        }
        #pragma unroll
        for (int nt = 0; nt < 4; ++nt) {
            const int row = bx * 128 + eh * 64 + nt * 16 + ml;
            float4 v;
            v.x = acc[mt][nt][0] + bb.x; v.y = acc[mt][nt][1] + bb.y;
            v.z = acc[mt][nt][2] + bb.z; v.w = acc[mt][nt][3] + bb.w;
            if (DOELU) { v.x = elu_f(v.x); v.y = elu_f(v.y); v.z = elu_f(v.z); v.w = elu_f(v.w); }
            ushort4 o; o.x = f2bf(v.x); o.y = f2bf(v.y); o.z = f2bf(v.z); o.w = f2bf(v.w);
            *(ushort4*)(C + (size_t)row * 256 + colb) = o;
        }
    }
}

// ---------------------------------------------------------------------------
// fp32 vector-ALU NT GEMM kept for the tiny node-level MLP3 (M=2560).
// ---------------------------------------------------------------------------
template<bool DOELU, typename TA, typename TC>
__global__ __launch_bounds__(256)
void gemm_nt(const TA* __restrict__ A, const float* __restrict__ W,
             const float* __restrict__ bias1,
             TC* __restrict__ C, int M, int Kdim)
{
    __shared__ float As[16][64];
    __shared__ float Ws[16][64];

    const int tid = threadIdx.x;
    const int am  = tid >> 2;
    const int ak  = (tid & 3) * 4;
    const int gm  = blockIdx.x * 64 + am;

    const TA* aptr0 = A + (size_t)gm * Kdim;
    const float* wptr = W + (size_t)(blockIdx.y * 64 + am) * Kdim;

    const int tx = tid & 15, ty = tid >> 4;
    float acc[4][4] = {};

    for (int k0 = 0; k0 < Kdim; k0 += 16) {
        const float4 a4 = ld4f(aptr0 + k0 + ak);
        const float4 w4 = *(const float4*)(wptr + k0 + (tid & 3) * 4);

        __syncthreads();
        As[ak+0][am] = a4.x; As[ak+1][am] = a4.y; As[ak+2][am] = a4.z; As[ak+3][am] = a4.w;
        const int wk = (tid & 3) * 4;
        Ws[wk+0][am] = w4.x; Ws[wk+1][am] = w4.y; Ws[wk+2][am] = w4.z; Ws[wk+3][am] = w4.w;
        __syncthreads();

        #pragma unroll
        for (int kq = 0; kq < 16; ++kq) {
            const float4 av = *(const float4*)&As[kq][ty * 4];
            const float4 wv = *(const float4*)&Ws[kq][tx * 4];
            const float a_[4] = {av.x, av.y, av.z, av.w};
            const float w_[4] = {wv.x, wv.y, wv.z, wv.w};
            #pragma unroll
            for (int i = 0; i < 4; ++i)
                #pragma unroll
                for (int j = 0; j < 4; ++j)
                    acc[i][j] += a_[i] * w_[j];
        }
    }

    const int gn = blockIdx.y * 64 + tx * 4;
    const float4 bb = *(const float4*)&bias1[gn];
    #pragma unroll
    for (int i = 0; i < 4; ++i) {
        const int row = blockIdx.x * 64 + ty * 4 + i;
        float4 o;
        o.x = acc[i][0] + bb.x; o.y = acc[i][1] + bb.y;
        o.z = acc[i][2] + bb.z; o.w = acc[i][3] + bb.w;
        if (DOELU) { o.x = elu_f(o.x); o.y = elu_f(o.y); o.z = elu_f(o.z); o.w = elu_f(o.w); }
        st4f(C + (size_t)row * 256 + gn, o);
    }
}

// ---------------------------------------------------------------------------
// edge2node scatter-add as deterministic gather: one block per (t,j).
// ---------------------------------------------------------------------------
__global__ __launch_bounds__(256)
void aggregate_kernel(const us* __restrict__ eSkip, const int* __restrict__ recv,
                      float* __restrict__ nAgg)
{
    const int t = blockIdx.x / N_;
    const int j = blockIdx.x - t * N_;
    const int c = threadIdx.x;
    const us* basep = eSkip + (size_t)t * E_ * H_;
    float acc = 0.f;
    for (int e = 0; e < E_; ++e) {
        if (recv[e] == j) acc += bf2f(basep[(size_t)e * H_ + c]);
    }
    nAgg[(size_t)blockIdx.x * H_ + c] = acc;
}

// ---------------------------------------------------------------------------
// LSTM recurrence over T. Gates G[T,E,256] (bf16) = e4@Wih^T+bih+bhh precomputed.
// ---------------------------------------------------------------------------
__global__ __launch_bounds__(256)
void lstm_kernel(const us* __restrict__ Gf, const us* __restrict__ Gr,
                 const float* __restrict__ fWhh, const float* __restrict__ rWhh,
                 float* __restrict__ hsF, float* __restrict__ hsR)
{
    const int NB = E_ / 8;
    const int bid = blockIdx.x;
    const bool revd = (bid >= NB);
    const int e0 = (revd ? bid - NB : bid) * 8;
    const us* G      = revd ? Gr : Gf;
    const float* Whh = revd ? rWhh : fWhh;
    float* hs        = revd ? hsR : hsF;
    const int tid = threadIdx.x;

    float4 w[16];
    #pragma unroll
    for (int qq = 0; qq < 16; ++qq) w[qq] = *(const float4*)(Whh + (size_t)tid * 64 + qq * 4);

    __shared__ float h_s[8][64];
    __shared__ float g_s[8][256];

    const int le0 = tid >> 6;
    const int r   = tid & 63;
    float c0 = 0.f, c1 = 0.f;
    h_s[le0][r] = 0.f;
    h_s[le0 + 4][r] = 0.f;
    __syncthreads();

    for (int s = 0; s < T_; ++s) {
        const int tt = revd ? (T_ - 1 - s) : s;
        const us* gRow = G + ((size_t)tt * E_ + e0) * 256;
        #pragma unroll
        for (int le = 0; le < 8; ++le) {
            float gv = bf2f(gRow[(size_t)le * 256 + tid]);
            const float4* hp = (const float4*)h_s[le];
            #pragma unroll
            for (int qq = 0; qq < 16; ++qq) {
                const float4 h4 = hp[qq];
                gv += h4.x*w[qq].x + h4.y*w[qq].y + h4.z*w[qq].z + h4.w*w[qq].w;
            }
            g_s[le][tid] = gv;
        }
        __syncthreads();
        float* hrow = hs + ((size_t)tt * E_ + e0) * 64;
        {
            const int le = le0;
            const float gi = g_s[le][r], gf = g_s[le][64 + r];
            const float gg = g_s[le][128 + r], go = g_s[le][192 + r];
            const float cc = sig_f(gf) * c0 + sig_f(gi) * tanh_f(gg);
            c0 = cc;
            const float hh = sig_f(go) * tanh_f(cc);
            h_s[le][r] = hh;
            hrow[(size_t)le * 64 + r] = hh;
        }
        {
            const int le = le0 + 4;
            const float gi = g_s[le][r], gf = g_s[le][64 + r];
            const float gg = g_s[le][128 + r], go = g_s[le][192 + r];
            const float cc = sig_f(gf) * c1 + sig_f(gi) * tanh_f(gg);
            c1 = cc;
            const float hh = sig_f(go) * tanh_f(cc);
            h_s[le][r] = hh;
            hrow[(size_t)le * 64 + r] = hh;
        }
        __syncthreads();
    }
}

// ---------------------------------------------------------------------------
__global__ __launch_bounds__(256)
void out_kernel(const float* __restrict__ hsF, const float* __restrict__ hsR,
                const float* __restrict__ priW, const float* __restrict__ prib,
                const float* __restrict__ encW, const float* __restrict__ encb,
                float* __restrict__ out)
{
    const int idx = blockIdx.x * 256 + threadIdx.x;
    const float* f = hsF + (size_t)idx * 64;
    const float* r = hsR + (size_t)idx * 64;
    float p0 = prib[0], p1 = prib[1], q0 = encb[0], q1 = encb[1];
    #pragma unroll
    for (int k4 = 0; k4 < 16; ++k4) {
        const float4 fv = *(const float4*)(f + k4 * 4);
        const float4 rv = *(const float4*)(r + k4 * 4);
        p0 += dot4(fv, *(const float4*)(priW + k4 * 4));
        p1 += dot4(fv, *(const float4*)(priW + 64 + k4 * 4));
        q0 += dot4(fv, *(const float4*)(encW + k4 * 4))
            + dot4(rv, *(const float4*)(encW + 64 + k4 * 4));
        q1 += dot4(fv, *(const float4*)(encW + 128 + k4 * 4))
            + dot4(rv, *(const float4*)(encW + 192 + k4 * 4));
    }
    float4 o; o.x = p0; o.y = p1; o.z = q0; o.w = q1;
    *(float4*)(out + (size_t)idx * 4) = o;
}

// ---------------------------------------------------------------------------
extern "C" void kernel_launch(void* const* d_in, const int* in_sizes, int n_in,
                              void* d_out, int out_size, void* d_ws, size_t ws_size,
                              hipStream_t stream)
{
    const float* x    = (const float*)d_in[0];
    const int*   send = (const int*)d_in[2];
    const int*   recv = (const int*)d_in[3];
    const float* m1W1 = (const float*)d_in[4];  const float* m1b1 = (const float*)d_in[5];
    const float* m1W2 = (const float*)d_in[6];  const float* m1b2 = (const float*)d_in[7];
    const float* m2W1 = (const float*)d_in[8];  const float* m2b1 = (const float*)d_in[9];
    const float* m2W2 = (const float*)d_in[10]; const float* m2b2 = (const float*)d_in[11];
    const float* m3W1 = (const float*)d_in[12]; const float* m3b1 = (const float*)d_in[13];
    const float* m3W2 = (const float*)d_in[14]; const float* m3b2 = (const float*)d_in[15];
    const float* m4W1 = (const float*)d_in[16]; const float* m4b1 = (const float*)d_in[17];
    const float* m4W2 = (const float*)d_in[18]; const float* m4b2 = (const float*)d_in[19];
    const float* fWih = (const float*)d_in[20]; const float* fWhh = (const float*)d_in[21];
    const float* fbih = (const float*)d_in[22]; const float* fbhh = (const float*)d_in[23];
    const float* rWih = (const float*)d_in[24]; const float* rWhh = (const float*)d_in[25];
    const float* rbih = (const float*)d_in[26]; const float* rbhh = (const float*)d_in[27];
    const float* encW = (const float*)d_in[28]; const float* encb = (const float*)d_in[29];
    const float* priW = (const float*)d_in[30]; const float* prib = (const float*)d_in[31];

    // --- workspace layout (~163.6 MB, <= round-2's verified 163.84 MB) ---
    const size_t SZN  = (size_t)TN_ * H_;     // node plane elems
    const size_t SZE  = (size_t)TE_ * H_;     // edge plane elems
    float* n_agg = (float*)d_ws;                          // [TN,256] f32
    float* m3t   = n_agg + SZN;                           // [TN,256] f32
    us* h16      = (us*)(m3t + SZN);                      // [TN,256] bf16
    us* n3       = h16 + SZN;                             // [TN,256] bf16
    // split weights (hi,lo pairs)
    us* w2aH = n3  + SZN;          us* w2aL = w2aH + 256*512;   // m2W1 [256,512]
    us* w2bH = w2aL + 256*512;     us* w2bL = w2bH + 256*256;   // m2W2 [256,256]
    us* w4aH = w2bL + 256*256;     us* w4aL = w4aH + 256*768;   // m4W1 [256,768]
    us* w4bH = w4aL + 256*768;     us* w4bL = w4bH + 256*256;   // m4W2 [256,256]
    us* wfiH = w4bL + 256*256;     us* wfiL = wfiH + 256*256;   // fWih [256,256]
    us* wriH = wfiL + 256*256;     us* wriL = wriH + 256*256;   // rWih [256,256]
    us* bufA16 = wriL + 256*256;                          // [TE,256] bf16
    us* bufB16 = bufA16 + SZE;                            // [TE,256] bf16
    us* bufC16 = bufB16 + SZE;                            // [TE,256] bf16
    float* hsF = (float*)bufC16;                          // alias: [TE,64] f32
    float* hsR = hsF + (size_t)TE_ * R_;                  // alias: [TE,64] f32
    const size_t needed = ((size_t)(bufC16 + SZE) - (size_t)d_ws);
    if (ws_size < needed) return;   // diagnostic: zero output == ws too small

    const dim3 gMF(TE_ / 128, 2), gN(TN_ / 64, 4);

    // 0. split weights into hi/lo bf16 planes (fp32-equivalent MFMA weights)
    wsplit_kernel<<<(256*512 + 255)/256, 256, 0, stream>>>(m2W1, w2aH, w2aL, 256*512);
    wsplit_kernel<<<(256*256 + 255)/256, 256, 0, stream>>>(m2W2, w2bH, w2bL, 256*256);
    wsplit_kernel<<<(256*768 + 255)/256, 256, 0, stream>>>(m4W1, w4aH, w4aL, 256*768);
    wsplit_kernel<<<(256*256 + 255)/256, 256, 0, stream>>>(m4W2, w4bH, w4bL, 256*256);
    wsplit_kernel<<<(256*256 + 255)/256, 256, 0, stream>>>(fWih, wfiH, wfiL, 256*256);
    wsplit_kernel<<<(256*256 + 255)/256, 256, 0, stream>>>(rWih, wriH, wriL, 256*256);

    // 1. node MLP -> h16 (bf16)
    mlp1_kernel<<<TN_ / 8, 256, 0, stream>>>(x, m1W1, m1b1, m1W2, m1b2, h16);
    // 2. mlp2 (gathered node2edge concat) -> skip
    gemm_mfma<1, true><<<gMF, 256, 0, stream>>>(h16, h16, nullptr, w2aH, w2aL, m2b1, nullptr, send, recv, bufA16, 512);
    gemm_mfma<0, true><<<gMF, 256, 0, stream>>>(bufA16, nullptr, nullptr, w2bH, w2bL, m2b2, nullptr, send, recv, bufB16, 256);
    // 3. edge->node aggregate + mlp3 (fp32 vector path, tiny)
    aggregate_kernel<<<TN_, 256, 0, stream>>>(bufB16, recv, n_agg);
    gemm_nt<true, float, float><<<gN, 256, 0, stream>>>(n_agg, m3W1, m3b1, m3t, TN_, 256);
    gemm_nt<true, float, us><<<gN, 256, 0, stream>>>(m3t, m3W2, m3b2, n3, TN_, 256);
    // 4. mlp4 (gathered n_send,n_recv,skip) -> e4
    gemm_mfma<2, true><<<gMF, 256, 0, stream>>>(n3, n3, bufB16, w4aH, w4aL, m4b1, nullptr, send, recv, bufA16, 768);
    gemm_mfma<0, true><<<gMF, 256, 0, stream>>>(bufA16, nullptr, nullptr, w4bH, w4bL, m4b2, nullptr, send, recv, bufC16, 256);
    // 5. LSTM pre-gates (bias = bih + bhh)
    gemm_mfma<0, false><<<gMF, 256, 0, stream>>>(bufC16, nullptr, nullptr, wfiH, wfiL, fbih, fbhh, send, recv, bufA16, 256);
    gemm_mfma<0, false><<<gMF, 256, 0, stream>>>(bufC16, nullptr, nullptr, wriH, wriL, rbih, rbhh, send, recv, bufB16, 256);
    // 6. recurrence (fwd + rev); writes hs over dead e4 buffer
    lstm_kernel<<<2 * (E_ / 8), 256, 0, stream>>>(bufA16, bufB16, fWhh, rWhh, hsF, hsR);
    // 7. output projections
    out_kernel<<<TE_ / 256, 256, 0, stream>>>(hsF, hsR, priW, prib, encW, encb, (float*)d_out);
}

// Round 4
// 958.455 us; speedup vs baseline: 2.3058x; 1.2158x over previous
//
#include <hip/hip_runtime.h>
#include <math.h>

#define T_ 64
#define N_ 40
#define D_ 4
#define H_ 256
#define R_ 64
#define E_ 1560
#define TE_ (T_*E_)   // 99840
#define TN_ (T_*N_)   // 2560

typedef unsigned short us;
typedef short short8 __attribute__((ext_vector_type(8)));
typedef float f32x4 __attribute__((ext_vector_type(4)));

__device__ __forceinline__ float elu_f(float x){ return x > 0.f ? x : (__expf(x) - 1.f); }
__device__ __forceinline__ float sig_f(float x){ return 1.f/(1.f+__expf(-x)); }
__device__ __forceinline__ float tanh_f(float x){ return 2.f/(1.f+__expf(-2.f*x)) - 1.f; }
__device__ __forceinline__ float dot4(float4 a, float4 b){ return a.x*b.x + a.y*b.y + a.z*b.z + a.w*b.w; }

__device__ __forceinline__ float bf2f(us u){ return __uint_as_float(((unsigned int)u) << 16); }
__device__ __forceinline__ us f2bf(float f){
    unsigned int u = __float_as_uint(f);
    u += 0x7FFFu + ((u >> 16) & 1u);
    return (us)(u >> 16);
}
__device__ __forceinline__ float4 ld4f(const float* p){ return *(const float4*)p; }
__device__ __forceinline__ float4 ld4f(const us* p){
    ushort4 v = *(const ushort4*)p;
    return make_float4(bf2f(v.x), bf2f(v.y), bf2f(v.z), bf2f(v.w));
}
__device__ __forceinline__ void st4f(float* p, float4 v){ *(float4*)p = v; }
__device__ __forceinline__ void st4f(us* p, float4 v){
    ushort4 o; o.x = f2bf(v.x); o.y = f2bf(v.y); o.z = f2bf(v.z); o.w = f2bf(v.w);
    *(ushort4*)p = o;
}

// async global->LDS, 16B per lane; lds dest must be wave-uniform (HW adds lane*16)
__device__ __forceinline__ void gld16(void* lds, const void* g){
    __builtin_amdgcn_global_load_lds((const __attribute__((address_space(1))) unsigned int*)g,
                                     (__attribute__((address_space(3))) unsigned int*)lds,
                                     16, 0, 0);
}

// ---------------------------------------------------------------------------
// weight split: W(fp32) -> hi = bf16(W), lo = bf16(W - hi). hi+lo ~ fp32.
// ---------------------------------------------------------------------------
__global__ __launch_bounds__(256)
void wsplit_kernel(const float* __restrict__ W, us* __restrict__ hi, us* __restrict__ lo, int n)
{
    const int i = blockIdx.x * 256 + threadIdx.x;
    if (i < n) {
        const float w = W[i];
        const us h = f2bf(w);
        hi[i] = h;
        lo[i] = f2bf(w - bf2f(h));
    }
}

// ---------------------------------------------------------------------------
// mlp1: x [TN,4] -> elu(elu(x W1^T + b1) W2^T + b2) -> h [TN,256] (bf16)
// ---------------------------------------------------------------------------
__global__ __launch_bounds__(256)
void mlp1_kernel(const float* __restrict__ x,
                 const float* __restrict__ W1, const float* __restrict__ b1,
                 const float* __restrict__ W2, const float* __restrict__ b2,
                 us* __restrict__ hout)
{
    __shared__ float xs[8][4];
    __shared__ float h1[8][256];
    const int tid = threadIdx.x;
    const int r0  = blockIdx.x * 8;

    if (tid < 32) xs[tid >> 2][tid & 3] = x[r0 * 4 + tid];
    __syncthreads();

    const float4 w1 = *(const float4*)&W1[tid * 4];
    const float bb1 = b1[tid];
    #pragma unroll
    for (int row = 0; row < 8; ++row) {
        float v = bb1 + xs[row][0]*w1.x + xs[row][1]*w1.y + xs[row][2]*w1.z + xs[row][3]*w1.w;
        h1[row][tid] = elu_f(v);
    }
    __syncthreads();

    float acc[8];
    const float bb2 = b2[tid];
    #pragma unroll
    for (int row = 0; row < 8; ++row) acc[row] = bb2;
    const float* w2row = W2 + (size_t)tid * 256;
    for (int k4 = 0; k4 < 64; ++k4) {
        const float4 w = *(const float4*)&w2row[k4 * 4];
        #pragma unroll
        for (int row = 0; row < 8; ++row) {
            const float4 hh = *(const float4*)&h1[row][k4 * 4];
            acc[row] += dot4(hh, w);
        }
    }
    #pragma unroll
    for (int row = 0; row < 8; ++row)
        hout[(size_t)(r0 + row) * 256 + tid] = f2bf(elu_f(acc[row]));
}

// ---------------------------------------------------------------------------
// MFMA NT GEMM: C[M,256](bf16) = act(A[M,K](bf16) @ (Whi+Wlo)[256,K]^T + b1(+b2))
// 128 edges x 128 features per block, BK=32, 4 waves, 16x16x32 bf16 MFMA.
// ---------------------------------------------------------------------------
template<int MODE, bool DOELU>
__global__ __launch_bounds__(256)
void gemm_mfma(const us* __restrict__ A, const us* __restrict__ A2, const us* __restrict__ A3,
               const us* __restrict__ Whi, const us* __restrict__ Wlo,
               const float* __restrict__ bias1, const float* __restrict__ bias2,
               const int* __restrict__ send, const int* __restrict__ recv,
               us* __restrict__ C, int Kdim)
{
    __shared__ char smem[24576];
    char* ldsA  = smem;            // 8KB edge tile
    char* ldsWh = smem + 8192;     // 8KB W-hi tile
    char* ldsWl = smem + 16384;    // 8KB W-lo tile

    const int tid  = threadIdx.x;
    const int lane = tid & 63;
    const int w    = tid >> 6;     // wave 0..3; stages k-plane w
    const int ml   = lane & 15;
    const int q    = lane >> 4;
    const int bx   = blockIdx.x;   // edge tile (128 rows)
    const int by   = blockIdx.y;   // feature tile (128 cols)
    const int eh   = w >> 1;       // edge half owned by this wave
    const int fh   = w & 1;        // feature half

    const int gr0 = bx * 128 + lane, gr1 = gr0 + 64;
    const us *pA0a=nullptr,*pA1a=nullptr,*pA2a=nullptr;
    const us *pA0b=nullptr,*pA1b=nullptr,*pA2b=nullptr;
    if (MODE == 0) {
        pA0a = A + (size_t)gr0 * Kdim;
        pA0b = A + (size_t)gr1 * Kdim;
    } else {
        const int t0 = gr0 / E_, e0 = gr0 - t0 * E_;
        const int t1 = gr1 / E_, e1 = gr1 - t1 * E_;
        pA0a = A  + ((size_t)(t0 * N_ + send[e0])) * H_;
        pA1a = A2 + ((size_t)(t0 * N_ + recv[e0])) * H_;
        pA0b = A  + ((size_t)(t1 * N_ + send[e1])) * H_;
        pA1b = A2 + ((size_t)(t1 * N_ + recv[e1])) * H_;
        if (MODE == 2) { pA2a = A3 + (size_t)gr0 * H_; pA2b = A3 + (size_t)gr1 * H_; }
    }
    const us* pWh0 = Whi + (size_t)(by * 128 + lane)      * Kdim;
    const us* pWh1 = Whi + (size_t)(by * 128 + 64 + lane) * Kdim;
    const us* pWl0 = Wlo + (size_t)(by * 128 + lane)      * Kdim;
    const us* pWl1 = Wlo + (size_t)(by * 128 + 64 + lane) * Kdim;

    f32x4 acc[4][4];
    #pragma unroll
    for (int i = 0; i < 4; ++i)
        #pragma unroll
        for (int j = 0; j < 4; ++j)
            acc[i][j] = (f32x4){0.f, 0.f, 0.f, 0.f};

    for (int k0 = 0; k0 < Kdim; k0 += 32) {
        __syncthreads();
        const int kk = k0 + w * 8;
        const us *sa, *sb;
        if (MODE == 0) { sa = pA0a + kk; sb = pA0b + kk; }
        else if (MODE == 1) {
            sa = (kk < 256) ? pA0a + kk : pA1a + (kk - 256);
            sb = (kk < 256) ? pA0b + kk : pA1b + (kk - 256);
        } else {
            sa = (kk < 256) ? pA0a + kk : (kk < 512) ? pA1a + (kk - 256) : pA2a + (kk - 512);
            sb = (kk < 256) ? pA0b + kk : (kk < 512) ? pA1b + (kk - 256) : pA2b + (kk - 512);
        }
        gld16(ldsA  + w * 2048,        sa);
        gld16(ldsA  + w * 2048 + 1024, sb);
        gld16(ldsWh + w * 2048,        pWh0 + kk);
        gld16(ldsWh + w * 2048 + 1024, pWh1 + kk);
        gld16(ldsWl + w * 2048,        pWl0 + kk);
        gld16(ldsWl + w * 2048 + 1024, pWl1 + kk);
        __builtin_amdgcn_s_waitcnt(0x3F70);  // vmcnt(0)
        __syncthreads();

        short8 wh[4], wl[4], ef[4];
        #pragma unroll
        for (int mt = 0; mt < 4; ++mt) {
            const int fr = fh * 64 + mt * 16 + ml;
            wh[mt] = *(const short8*)(ldsWh + q * 2048 + fr * 16);
            wl[mt] = *(const short8*)(ldsWl + q * 2048 + fr * 16);
        }
        #pragma unroll
        for (int nt = 0; nt < 4; ++nt) {
            const int er = eh * 64 + nt * 16 + ml;
            ef[nt] = *(const short8*)(ldsA + q * 2048 + er * 16);
        }
        #pragma unroll
        for (int mt = 0; mt < 4; ++mt)
            #pragma unroll
            for (int nt = 0; nt < 4; ++nt) {
                acc[mt][nt] = __builtin_amdgcn_mfma_f32_16x16x32_bf16(wh[mt], ef[nt], acc[mt][nt], 0, 0, 0);
                acc[mt][nt] = __builtin_amdgcn_mfma_f32_16x16x32_bf16(wl[mt], ef[nt], acc[mt][nt], 0, 0, 0);
            }
    }

    #pragma unroll
    for (int mt = 0; mt < 4; ++mt) {
        const int colb = by * 128 + fh * 64 + mt * 16 + q * 4;
        float4 bb = *(const float4*)(bias1 + colb);
        if (bias2) {
            const float4 b2 = *(const float4*)(bias2 + colb);
            bb.x += b2.x; bb.y += b2.y; bb.z += b2.z; bb.w += b2.w;
        }
        #pragma unroll
        for (int nt = 0; nt < 4; ++nt) {
            const int row = bx * 128 + eh * 64 + nt * 16 + ml;
            float4 v;
            v.x = acc[mt][nt][0] + bb.x; v.y = acc[mt][nt][1] + bb.y;
            v.z = acc[mt][nt][2] + bb.z; v.w = acc[mt][nt][3] + bb.w;
            if (DOELU) { v.x = elu_f(v.x); v.y = elu_f(v.y); v.z = elu_f(v.z); v.w = elu_f(v.w); }
            ushort4 o; o.x = f2bf(v.x); o.y = f2bf(v.y); o.z = f2bf(v.z); o.w = f2bf(v.w);
            *(ushort4*)(C + (size_t)row * 256 + colb) = o;
        }
    }
}

// ---------------------------------------------------------------------------
// fp32 vector-ALU NT GEMM for the tiny node-level MLP3 (M=2560).
// ---------------------------------------------------------------------------
template<bool DOELU, typename TA, typename TC>
__global__ __launch_bounds__(256)
void gemm_nt(const TA* __restrict__ A, const float* __restrict__ W,
             const float* __restrict__ bias1,
             TC* __restrict__ C, int M, int Kdim)
{
    __shared__ float As[16][64];
    __shared__ float Ws[16][64];

    const int tid = threadIdx.x;
    const int am  = tid >> 2;
    const int ak  = (tid & 3) * 4;
    const int gm  = blockIdx.x * 64 + am;

    const TA* aptr0 = A + (size_t)gm * Kdim;
    const float* wptr = W + (size_t)(blockIdx.y * 64 + am) * Kdim;

    const int tx = tid & 15, ty = tid >> 4;
    float acc[4][4] = {};

    for (int k0 = 0; k0 < Kdim; k0 += 16) {
        const float4 a4 = ld4f(aptr0 + k0 + ak);
        const float4 w4 = *(const float4*)(wptr + k0 + (tid & 3) * 4);

        __syncthreads();
        As[ak+0][am] = a4.x; As[ak+1][am] = a4.y; As[ak+2][am] = a4.z; As[ak+3][am] = a4.w;
        const int wk = (tid & 3) * 4;
        Ws[wk+0][am] = w4.x; Ws[wk+1][am] = w4.y; Ws[wk+2][am] = w4.z; Ws[wk+3][am] = w4.w;
        __syncthreads();

        #pragma unroll
        for (int kq = 0; kq < 16; ++kq) {
            const float4 av = *(const float4*)&As[kq][ty * 4];
            const float4 wv = *(const float4*)&Ws[kq][tx * 4];
            const float a_[4] = {av.x, av.y, av.z, av.w};
            const float w_[4] = {wv.x, wv.y, wv.z, wv.w};
            #pragma unroll
            for (int i = 0; i < 4; ++i)
                #pragma unroll
                for (int j = 0; j < 4; ++j)
                    acc[i][j] += a_[i] * w_[j];
        }
    }

    const int gn = blockIdx.y * 64 + tx * 4;
    const float4 bb = *(const float4*)&bias1[gn];
    #pragma unroll
    for (int i = 0; i < 4; ++i) {
        const int row = blockIdx.x * 64 + ty * 4 + i;
        float4 o;
        o.x = acc[i][0] + bb.x; o.y = acc[i][1] + bb.y;
        o.z = acc[i][2] + bb.z; o.w = acc[i][3] + bb.w;
        if (DOELU) { o.x = elu_f(o.x); o.y = elu_f(o.y); o.z = elu_f(o.z); o.w = elu_f(o.w); }
        st4f(C + (size_t)row * 256 + gn, o);
    }
}

// ---------------------------------------------------------------------------
// edge2node scatter-add as deterministic gather: one block per (t,j).
// ---------------------------------------------------------------------------
__global__ __launch_bounds__(256)
void aggregate_kernel(const us* __restrict__ eSkip, const int* __restrict__ recv,
                      float* __restrict__ nAgg)
{
    const int t = blockIdx.x / N_;
    const int j = blockIdx.x - t * N_;
    const int c = threadIdx.x;
    const us* basep = eSkip + (size_t)t * E_ * H_;
    float acc = 0.f;
    for (int e = 0; e < E_; ++e) {
        if (recv[e] == j) acc += bf2f(basep[(size_t)e * H_ + c]);
    }
    nAgg[(size_t)blockIdx.x * H_ + c] = acc;
}

// ---------------------------------------------------------------------------
// LSTM recurrence over T. Gates G[T,E,256] (bf16) = e4@Wih^T+bih+bhh precomputed.
// v2: 4 edges/block (780 blocks, ~3 blocks/CU) + 1-step software prefetch of
// the (state-independent) gate loads to hide HBM/L3 latency behind the h.Whh
// dot chain. Per-thread accumulation order identical to v1 -> bit-identical.
// ---------------------------------------------------------------------------
__global__ __launch_bounds__(256)
void lstm_kernel(const us* __restrict__ Gf, const us* __restrict__ Gr,
                 const float* __restrict__ fWhh, const float* __restrict__ rWhh,
                 float* __restrict__ hsF, float* __restrict__ hsR)
{
    const int NB = E_ / 4;   // 390 blocks per direction
    const int bid = blockIdx.x;
    const bool revd = (bid >= NB);
    const int e0 = (revd ? bid - NB : bid) * 4;
    const us* G      = revd ? Gr : Gf;
    const float* Whh = revd ? rWhh : fWhh;
    float* hs        = revd ? hsR : hsF;
    const int tid = threadIdx.x;

    float4 w[16];
    #pragma unroll
    for (int qq = 0; qq < 16; ++qq) w[qq] = *(const float4*)(Whh + (size_t)tid * 64 + qq * 4);

    __shared__ float h_s[4][64];
    __shared__ float g_s[4][256];

    const int le0 = tid >> 6;      // wave id 0..3 = edge owned in pointwise
    const int r   = tid & 63;
    float c0 = 0.f;
    h_s[le0][r] = 0.f;
    __syncthreads();

    us gcur[4], gnxt[4];
    {
        const int tt0 = revd ? (T_ - 1) : 0;
        const us* g0 = G + ((size_t)tt0 * E_ + e0) * 256 + tid;
        #pragma unroll
        for (int le = 0; le < 4; ++le) gcur[le] = g0[(size_t)le * 256];
    }

    for (int s = 0; s < T_; ++s) {
        const int tt = revd ? (T_ - 1 - s) : s;
        // prefetch next step's gates (state-independent)
        const int sn = (s + 1 < T_) ? s + 1 : s;
        const int tn = revd ? (T_ - 1 - sn) : sn;
        const us* gn = G + ((size_t)tn * E_ + e0) * 256 + tid;
        #pragma unroll
        for (int le = 0; le < 4; ++le) gnxt[le] = gn[(size_t)le * 256];

        #pragma unroll
        for (int le = 0; le < 4; ++le) {
            float gv = bf2f(gcur[le]);
            const float4* hp = (const float4*)h_s[le];
            #pragma unroll
            for (int qq = 0; qq < 16; ++qq) {
                const float4 h4 = hp[qq];
                gv += h4.x*w[qq].x + h4.y*w[qq].y + h4.z*w[qq].z + h4.w*w[qq].w;
            }
            g_s[le][tid] = gv;
        }
        __syncthreads();
        float* hrow = hs + ((size_t)tt * E_ + e0) * 64;
        {
            const float gi = g_s[le0][r], gf = g_s[le0][64 + r];
            const float gg = g_s[le0][128 + r], go = g_s[le0][192 + r];
            const float cc = sig_f(gf) * c0 + sig_f(gi) * tanh_f(gg);
            c0 = cc;
            const float hh = sig_f(go) * tanh_f(cc);
            h_s[le0][r] = hh;
            hrow[(size_t)le0 * 64 + r] = hh;
        }
        __syncthreads();
        #pragma unroll
        for (int le = 0; le < 4; ++le) gcur[le] = gnxt[le];
    }
}

// ---------------------------------------------------------------------------
__global__ __launch_bounds__(256)
void out_kernel(const float* __restrict__ hsF, const float* __restrict__ hsR,
                const float* __restrict__ priW, const float* __restrict__ prib,
                const float* __restrict__ encW, const float* __restrict__ encb,
                float* __restrict__ out)
{
    const int idx = blockIdx.x * 256 + threadIdx.x;
    const float* f = hsF + (size_t)idx * 64;
    const float* r = hsR + (size_t)idx * 64;
    float p0 = prib[0], p1 = prib[1], q0 = encb[0], q1 = encb[1];
    #pragma unroll
    for (int k4 = 0; k4 < 16; ++k4) {
        const float4 fv = *(const float4*)(f + k4 * 4);
        const float4 rv = *(const float4*)(r + k4 * 4);
        p0 += dot4(fv, *(const float4*)(priW + k4 * 4));
        p1 += dot4(fv, *(const float4*)(priW + 64 + k4 * 4));
        q0 += dot4(fv, *(const float4*)(encW + k4 * 4))
            + dot4(rv, *(const float4*)(encW + 64 + k4 * 4));
        q1 += dot4(fv, *(const float4*)(encW + 128 + k4 * 4))
            + dot4(rv, *(const float4*)(encW + 192 + k4 * 4));
    }
    float4 o; o.x = p0; o.y = p1; o.z = q0; o.w = q1;
    *(float4*)(out + (size_t)idx * 4) = o;
}

// ---------------------------------------------------------------------------
extern "C" void kernel_launch(void* const* d_in, const int* in_sizes, int n_in,
                              void* d_out, int out_size, void* d_ws, size_t ws_size,
                              hipStream_t stream)
{
    const float* x    = (const float*)d_in[0];
    const int*   send = (const int*)d_in[2];
    const int*   recv = (const int*)d_in[3];
    const float* m1W1 = (const float*)d_in[4];  const float* m1b1 = (const float*)d_in[5];
    const float* m1W2 = (const float*)d_in[6];  const float* m1b2 = (const float*)d_in[7];
    const float* m2W1 = (const float*)d_in[8];  const float* m2b1 = (const float*)d_in[9];
    const float* m2W2 = (const float*)d_in[10]; const float* m2b2 = (const float*)d_in[11];
    const float* m3W1 = (const float*)d_in[12]; const float* m3b1 = (const float*)d_in[13];
    const float* m3W2 = (const float*)d_in[14]; const float* m3b2 = (const float*)d_in[15];
    const float* m4W1 = (const float*)d_in[16]; const float* m4b1 = (const float*)d_in[17];
    const float* m4W2 = (const float*)d_in[18]; const float* m4b2 = (const float*)d_in[19];
    const float* fWih = (const float*)d_in[20]; const float* fWhh = (const float*)d_in[21];
    const float* fbih = (const float*)d_in[22]; const float* fbhh = (const float*)d_in[23];
    const float* rWih = (const float*)d_in[24]; const float* rWhh = (const float*)d_in[25];
    const float* rbih = (const float*)d_in[26]; const float* rbhh = (const float*)d_in[27];
    const float* encW = (const float*)d_in[28]; const float* encb = (const float*)d_in[29];
    const float* priW = (const float*)d_in[30]; const float* prib = (const float*)d_in[31];

    const size_t SZN  = (size_t)TN_ * H_;
    const size_t SZE  = (size_t)TE_ * H_;
    float* n_agg = (float*)d_ws;
    float* m3t   = n_agg + SZN;
    us* h16      = (us*)(m3t + SZN);
    us* n3       = h16 + SZN;
    us* w2aH = n3  + SZN;          us* w2aL = w2aH + 256*512;
    us* w2bH = w2aL + 256*512;     us* w2bL = w2bH + 256*256;
    us* w4aH = w2bL + 256*256;     us* w4aL = w4aH + 256*768;
    us* w4bH = w4aL + 256*768;     us* w4bL = w4bH + 256*256;
    us* wfiH = w4bL + 256*256;     us* wfiL = wfiH + 256*256;
    us* wriH = wfiL + 256*256;     us* wriL = wriH + 256*256;
    us* bufA16 = wriL + 256*256;
    us* bufB16 = bufA16 + SZE;
    us* bufC16 = bufB16 + SZE;
    float* hsF = (float*)bufC16;
    float* hsR = hsF + (size_t)TE_ * R_;
    const size_t needed = ((size_t)(bufC16 + SZE) - (size_t)d_ws);
    if (ws_size < needed) return;

    const dim3 gMF(TE_ / 128, 2), gN(TN_ / 64, 4);

    // 0. split weights into hi/lo bf16 planes
    wsplit_kernel<<<(256*512 + 255)/256, 256, 0, stream>>>(m2W1, w2aH, w2aL, 256*512);
    wsplit_kernel<<<(256*256 + 255)/256, 256, 0, stream>>>(m2W2, w2bH, w2bL, 256*256);
    wsplit_kernel<<<(256*768 + 255)/256, 256, 0, stream>>>(m4W1, w4aH, w4aL, 256*768);
    wsplit_kernel<<<(256*256 + 255)/256, 256, 0, stream>>>(m4W2, w4bH, w4bL, 256*256);
    wsplit_kernel<<<(256*256 + 255)/256, 256, 0, stream>>>(fWih, wfiH, wfiL, 256*256);
    wsplit_kernel<<<(256*256 + 255)/256, 256, 0, stream>>>(rWih, wriH, wriL, 256*256);

    // 1. node MLP -> h16 (bf16)
    mlp1_kernel<<<TN_ / 8, 256, 0, stream>>>(x, m1W1, m1b1, m1W2, m1b2, h16);
    // 2. mlp2 (gathered node2edge concat) -> skip
    gemm_mfma<1, true><<<gMF, 256, 0, stream>>>(h16, h16, nullptr, w2aH, w2aL, m2b1, nullptr, send, recv, bufA16, 512);
    gemm_mfma<0, true><<<gMF, 256, 0, stream>>>(bufA16, nullptr, nullptr, w2bH, w2bL, m2b2, nullptr, send, recv, bufB16, 256);
    // 3. edge->node aggregate + mlp3 (fp32 vector path, tiny)
    aggregate_kernel<<<TN_, 256, 0, stream>>>(bufB16, recv, n_agg);
    gemm_nt<true, float, float><<<gN, 256, 0, stream>>>(n_agg, m3W1, m3b1, m3t, TN_, 256);
    gemm_nt<true, float, us><<<gN, 256, 0, stream>>>(m3t, m3W2, m3b2, n3, TN_, 256);
    // 4. mlp4 (gathered n_send,n_recv,skip) -> e4
    gemm_mfma<2, true><<<gMF, 256, 0, stream>>>(n3, n3, bufB16, w4aH, w4aL, m4b1, nullptr, send, recv, bufA16, 768);
    gemm_mfma<0, true><<<gMF, 256, 0, stream>>>(bufA16, nullptr, nullptr, w4bH, w4bL, m4b2, nullptr, send, recv, bufC16, 256);
    // 5. LSTM pre-gates (bias = bih + bhh)
    gemm_mfma<0, false><<<gMF, 256, 0, stream>>>(bufC16, nullptr, nullptr, wfiH, wfiL, fbih, fbhh, send, recv, bufA16, 256);
    gemm_mfma<0, false><<<gMF, 256, 0, stream>>>(bufC16, nullptr, nullptr, wriH, wriL, rbih, rbhh, send, recv, bufB16, 256);
    // 6. recurrence v2: 4 edges/block + gate prefetch
    lstm_kernel<<<2 * (E_ / 4), 256, 0, stream>>>(bufA16, bufB16, fWhh, rWhh, hsF, hsR);
    // 7. output projections
    out_kernel<<<TE_ / 256, 256, 0, stream>>>(hsF, hsR, priW, prib, encW, encb, (float*)d_out);
}

// Round 7
// 839.750 us; speedup vs baseline: 2.6317x; 1.1414x over previous
//
#include <hip/hip_runtime.h>
#include <math.h>

#define T_ 64
#define N_ 40
#define D_ 4
#define H_ 256
#define R_ 64
#define E_ 1560
#define TE_ (T_*E_)
#define TN_ (T_*N_)

typedef unsigned short us;
typedef short short8 __attribute__((ext_vector_type(8)));
typedef float f32x4 __attribute__((ext_vector_type(4)));

__device__ __forceinline__ float elu_f(float x){ return x > 0.f ? x : (__expf(x) - 1.f); }
__device__ __forceinline__ float sig_f(float x){ return 1.f/(1.f+__expf(-x)); }
__device__ __forceinline__ float tanh_f(float x){ return 2.f/(1.f+__expf(-2.f*x)) - 1.f; }
__device__ __forceinline__ float dot4(float4 a, float4 b){ return a.x*b.x + a.y*b.y + a.z*b.z + a.w*b.w; }

__device__ __forceinline__ float bf2f(us u){ return __uint_as_float(((unsigned int)u) << 16); }
__device__ __forceinline__ us f2bf(float f){
    unsigned int u = __float_as_uint(f);
    u += 0x7FFFu + ((u >> 16) & 1u);
    return (us)(u >> 16);
}
__device__ __forceinline__ float4 ld4f(const float* p){ return *(const float4*)p; }
__device__ __forceinline__ float4 ld4f(const us* p){
    ushort4 v = *(const ushort4*)p;
    return make_float4(bf2f(v.x), bf2f(v.y), bf2f(v.z), bf2f(v.w));
}
__device__ __forceinline__ void st4f(float* p, float4 v){ *(float4*)p = v; }
__device__ __forceinline__ void st4f(us* p, float4 v){
    ushort4 o; o.x = f2bf(v.x); o.y = f2bf(v.y); o.z = f2bf(v.z); o.w = f2bf(v.w);
    *(ushort4*)p = o;
}

__device__ __forceinline__ void gld16(void* lds, const void* g){
    __builtin_amdgcn_global_load_lds((const __attribute__((address_space(1))) unsigned int*)g,
                                     (__attribute__((address_space(3))) unsigned int*)lds,
                                     16, 0, 0);
}

__device__ __forceinline__ void wsplit1(const float* W, us* hi, us* lo, int i){
    const float w = W[i];
    const us h = f2bf(w);
    hi[i] = h;
    lo[i] = f2bf(w - bf2f(h));
}

__global__ __launch_bounds__(256)
void wsplit_all(const float* __restrict__ s0, us* h0, us* l0,
                const float* __restrict__ s1, us* h1, us* l1,
                const float* __restrict__ s2, us* h2, us* l2,
                const float* __restrict__ s3, us* h3, us* l3,
                const float* __restrict__ s4, us* h4, us* l4,
                const float* __restrict__ s5, us* h5, us* l5,
                const float* __restrict__ s6, us* h6, us* l6,
                const float* __restrict__ s7, us* h7, us* l7)
{
    int i = blockIdx.x * 256 + threadIdx.x;
    if (i < 131072) { wsplit1(s0, h0, l0, i); return; } i -= 131072;
    if (i <  65536) { wsplit1(s1, h1, l1, i); return; } i -=  65536;
    if (i < 196608) { wsplit1(s2, h2, l2, i); return; } i -= 196608;
    if (i <  65536) { wsplit1(s3, h3, l3, i); return; } i -=  65536;
    if (i <  65536) { wsplit1(s4, h4, l4, i); return; } i -=  65536;
    if (i <  65536) { wsplit1(s5, h5, l5, i); return; } i -=  65536;
    if (i <  16384) { wsplit1(s6, h6, l6, i); return; } i -=  16384;
    wsplit1(s7, h7, l7, i);
}

__global__ __launch_bounds__(256)
void mlp1_kernel(const float* __restrict__ x,
                 const float* __restrict__ W1, const float* __restrict__ b1,
                 const float* __restrict__ W2, const float* __restrict__ b2,
                 us* __restrict__ hout)
{
    __shared__ float xs[8][4];
    __shared__ float h1[8][256];
    const int tid = threadIdx.x;
    const int r0  = blockIdx.x * 8;

    if (tid < 32) xs[tid >> 2][tid & 3] = x[r0 * 4 + tid];
    __syncthreads();

    const float4 w1 = *(const float4*)&W1[tid * 4];
    const float bb1 = b1[tid];
    #pragma unroll
    for (int row = 0; row < 8; ++row) {
        float v = bb1 + xs[row][0]*w1.x + xs[row][1]*w1.y + xs[row][2]*w1.z + xs[row][3]*w1.w;
        h1[row][tid] = elu_f(v);
    }
    __syncthreads();

    float acc[8];
    const float bb2 = b2[tid];
    #pragma unroll
    for (int row = 0; row < 8; ++row) acc[row] = bb2;
    const float* w2row = W2 + (size_t)tid * 256;
    for (int k4 = 0; k4 < 64; ++k4) {
        const float4 w = *(const float4*)&w2row[k4 * 4];
        #pragma unroll
        for (int row = 0; row < 8; ++row) {
            const float4 hh = *(const float4*)&h1[row][k4 * 4];
            acc[row] += dot4(hh, w);
        }
    }
    #pragma unroll
    for (int row = 0; row < 8; ++row)
        hout[(size_t)(r0 + row) * 256 + tid] = f2bf(elu_f(acc[row]));
}

template<int MODE, bool DOELU>
__global__ __launch_bounds__(256)
void gemm_mfma(const us* __restrict__ A, const us* __restrict__ A2, const us* __restrict__ A3,
               const us* __restrict__ Whi, const us* __restrict__ Wlo,
               const float* __restrict__ bias1, const float* __restrict__ bias2,
               const int* __restrict__ send, const int* __restrict__ recv,
               us* __restrict__ C, int Kdim)
{
    __shared__ char smem[24576];
    char* ldsA  = smem;
    char* ldsWh = smem + 8192;
    char* ldsWl = smem + 16384;

    const int tid  = threadIdx.x;
    const int lane = tid & 63;
    const int w    = tid >> 6;
    const int ml   = lane & 15;
    const int q    = lane >> 4;
    const int bx   = blockIdx.x;
    const int by   = blockIdx.y;
    const int eh   = w >> 1;
    const int fh   = w & 1;

    const int gr0 = bx * 128 + lane, gr1 = gr0 + 64;
    const us *pA0a=nullptr,*pA1a=nullptr,*pA2a=nullptr;
    const us *pA0b=nullptr,*pA1b=nullptr,*pA2b=nullptr;
    if (MODE == 0) {
        pA0a = A + (size_t)gr0 * Kdim;
        pA0b = A + (size_t)gr1 * Kdim;
    } else {
        const int t0 = gr0 / E_, e0 = gr0 - t0 * E_;
        const int t1 = gr1 / E_, e1 = gr1 - t1 * E_;
        pA0a = A  + ((size_t)(t0 * N_ + send[e0])) * H_;
        pA1a = A2 + ((size_t)(t0 * N_ + recv[e0])) * H_;
        pA0b = A  + ((size_t)(t1 * N_ + send[e1])) * H_;
        pA1b = A2 + ((size_t)(t1 * N_ + recv[e1])) * H_;
        if (MODE == 2) { pA2a = A3 + (size_t)gr0 * H_; pA2b = A3 + (size_t)gr1 * H_; }
    }
    const us* pWh0 = Whi + (size_t)(by * 128 + lane)      * Kdim;
    const us* pWh1 = Whi + (size_t)(by * 128 + 64 + lane) * Kdim;
    const us* pWl0 = Wlo + (size_t)(by * 128 + lane)      * Kdim;
    const us* pWl1 = Wlo + (size_t)(by * 128 + 64 + lane) * Kdim;

    f32x4 acc[4][4];
    #pragma unroll
    for (int i = 0; i < 4; ++i)
        #pragma unroll
        for (int j = 0; j < 4; ++j)
            acc[i][j] = (f32x4){0.f, 0.f, 0.f, 0.f};

    for (int k0 = 0; k0 < Kdim; k0 += 32) {
        __syncthreads();
        const int kk = k0 + w * 8;
        const us *sa, *sb;
        if (MODE == 0) { sa = pA0a + kk; sb = pA0b + kk; }
        else if (MODE == 1) {
            sa = (kk < 256) ? pA0a + kk : pA1a + (kk - 256);
            sb = (kk < 256) ? pA0b + kk : pA1b + (kk - 256);
        } else {
            sa = (kk < 256) ? pA0a + kk : (kk < 512) ? pA1a + (kk - 256) : pA2a + (kk - 512);
            sb = (kk < 256) ? pA0b + kk : (kk < 512) ? pA1b + (kk - 256) : pA2b + (kk - 512);
        }
        gld16(ldsA  + w * 2048,        sa);
        gld16(ldsA  + w * 2048 + 1024, sb);
        gld16(ldsWh + w * 2048,        pWh0 + kk);
        gld16(ldsWh + w * 2048 + 1024, pWh1 + kk);
        gld16(ldsWl + w * 2048,        pWl0 + kk);
        gld16(ldsWl + w * 2048 + 1024, pWl1 + kk);
        __builtin_amdgcn_s_waitcnt(0x3F70);
        __syncthreads();

        short8 wh[4], wl[4], ef[4];
        #pragma unroll
        for (int mt = 0; mt < 4; ++mt) {
            const int fr = fh * 64 + mt * 16 + ml;
            wh[mt] = *(const short8*)(ldsWh + q * 2048 + fr * 16);
            wl[mt] = *(const short8*)(ldsWl + q * 2048 + fr * 16);
        }
        #pragma unroll
        for (int nt = 0; nt < 4; ++nt) {
            const int er = eh * 64 + nt * 16 + ml;
            ef[nt] = *(const short8*)(ldsA + q * 2048 + er * 16);
        }
        #pragma unroll
        for (int mt = 0; mt < 4; ++mt)
            #pragma unroll
            for (int nt = 0; nt < 4; ++nt) {
                acc[mt][nt] = __builtin_amdgcn_mfma_f32_16x16x32_bf16(wh[mt], ef[nt], acc[mt][nt], 0, 0, 0);
                acc[mt][nt] = __builtin_amdgcn_mfma_f32_16x16x32_bf16(wl[mt], ef[nt], acc[mt][nt], 0, 0, 0);
            }
    }

    #pragma unroll
    for (int mt = 0; mt < 4; ++mt) {
        const int colb = by * 128 + fh * 64 + mt * 16 + q * 4;
        float4 bb = *(const float4*)(bias1 + colb);
        if (bias2) {
            const float4 b2 = *(const float4*)(bias2 + colb);
            bb.x += b2.x; bb.y += b2.y; bb.z += b2.z; bb.w += b2.w;
        }
        #pragma unroll
        for (int nt = 0; nt < 4; ++nt) {
            const int row = bx * 128 + eh * 64 + nt * 16 + ml;
            float4 v;
            v.x = acc[mt][nt][0] + bb.x; v.y = acc[mt][nt][1] + bb.y;
            v.z = acc[mt][nt][2] + bb.z; v.w = acc[mt][nt][3] + bb.w;
            if (DOELU) { v.x = elu_f(v.x); v.y = elu_f(v.y); v.z = elu_f(v.z); v.w = elu_f(v.w); }
            ushort4 o; o.x = f2bf(v.x); o.y = f2bf(v.y); o.z = f2bf(v.z); o.w = f2bf(v.w);
            *(ushort4*)(C + (size_t)row * 256 + colb) = o;
        }
    }
}

template<bool DOELU, typename TA, typename TC>
__global__ __launch_bounds__(256)
void gemm_nt(const TA* __restrict__ A, const float* __restrict__ W,
             const float* __restrict__ bias1,
             TC* __restrict__ C, int M, int Kdim)
{
    __shared__ float As[16][64];
    __shared__ float Ws[16][64];

    const int tid = threadIdx.x;
    const int am  = tid >> 2;
    const int ak  = (tid & 3) * 4;
    const int gm  = blockIdx.x * 64 + am;

    const TA* aptr0 = A + (size_t)gm * Kdim;
    const float* wptr = W + (size_t)(blockIdx.y * 64 + am) * Kdim;

    const int tx = tid & 15, ty = tid >> 4;
    float acc[4][4] = {};

    for (int k0 = 0; k0 < Kdim; k0 += 16) {
        const float4 a4 = ld4f(aptr0 + k0 + ak);
        const float4 w4 = *(const float4*)(wptr + k0 + (tid & 3) * 4);

        __syncthreads();
        As[ak+0][am] = a4.x; As[ak+1][am] = a4.y; As[ak+2][am] = a4.z; As[ak+3][am] = a4.w;
        const int wk = (tid & 3) * 4;
        Ws[wk+0][am] = w4.x; Ws[wk+1][am] = w4.y; Ws[wk+2][am] = w4.z; Ws[wk+3][am] = w4.w;
        __syncthreads();

        #pragma unroll
        for (int kq = 0; kq < 16; ++kq) {
            const float4 av = *(const float4*)&As[kq][ty * 4];
            const float4 wv = *(const float4*)&Ws[kq][tx * 4];
            const float a_[4] = {av.x, av.y, av.z, av.w};
            const float w_[4] = {wv.x, wv.y, wv.z, wv.w};
            #pragma unroll
            for (int i = 0; i < 4; ++i)
                #pragma unroll
                for (int j = 0; j < 4; ++j)
                    acc[i][j] += a_[i] * w_[j];
        }
    }

    const int gn = blockIdx.y * 64 + tx * 4;
    const float4 bb = *(const float4*)&bias1[gn];
    #pragma unroll
    for (int i = 0; i < 4; ++i) {
        const int row = blockIdx.x * 64 + ty * 4 + i;
        float4 o;
        o.x = acc[i][0] + bb.x; o.y = acc[i][1] + bb.y;
        o.z = acc[i][2] + bb.z; o.w = acc[i][3] + bb.w;
        if (DOELU) { o.x = elu_f(o.x); o.y = elu_f(o.y); o.z = elu_f(o.z); o.w = elu_f(o.w); }
        st4f(C + (size_t)row * 256 + gn, o);
    }
}

__global__ __launch_bounds__(256)
void aggregate_kernel(const us* __restrict__ eSkip, const int* __restrict__ recv,
                      float* __restrict__ nAgg)
{
    const int t = blockIdx.x / N_;
    const int j = blockIdx.x - t * N_;
    const int c = threadIdx.x;
    const us* basep = eSkip + (size_t)t * E_ * H_;
    float acc = 0.f;
    for (int e = 0; e < E_; ++e) {
        if (recv[e] == j) acc += bf2f(basep[(size_t)e * H_ + c]);
    }
    nAgg[(size_t)blockIdx.x * H_ + c] = acc;
}

// LSTM recurrence v3: MFMA recurrent GEMM. One block = 16 edges, one direction.
// Wave w owns gate type w. Whh split hi/lo bf16 in registers; h split hi/lo
// bf16 per step in LDS; 3 MFMA products ~= fp32 (lo*lo dropped, ~2^-16).
__global__ __launch_bounds__(256)
void lstm_mfma(const us* __restrict__ Gf, const us* __restrict__ Gr,
               const us* __restrict__ fWhhH, const us* __restrict__ fWhhL,
               const us* __restrict__ rWhhH, const us* __restrict__ rWhhL,
               float* __restrict__ hsF, float* __restrict__ hsR)
{
    const int NBD = (E_ + 15) / 16;
    const bool revd = (int)blockIdx.x >= NBD;
    const int blk = revd ? (int)blockIdx.x - NBD : (int)blockIdx.x;
    const int e0 = blk * 16;
    const us* G  = revd ? Gr : Gf;
    const us* WH = revd ? rWhhH : fWhhH;
    const us* WL = revd ? rWhhL : fWhhL;
    float* hs    = revd ? hsR : hsF;

    const int tid  = threadIdx.x;
    const int lane = tid & 63;
    const int w    = tid >> 6;
    const int ml   = lane & 15;
    const int q    = lane >> 4;

    __shared__ float g_s[4][16][68];
    __shared__ us hHi[16][72];
    __shared__ us hLo[16][72];

    short8 wfh[4][2], wfl[4][2];
    #pragma unroll
    for (int mt = 0; mt < 4; ++mt) {
        const int row = w * 64 + mt * 16 + ml;
        #pragma unroll
        for (int ks = 0; ks < 2; ++ks) {
            wfh[mt][ks] = *(const short8*)(WH + (size_t)row * 64 + ks * 32 + q * 8);
            wfl[mt][ks] = *(const short8*)(WL + (size_t)row * 64 + ks * 32 + q * 8);
        }
    }

    for (int i = tid; i < 16 * 72; i += 256) { ((us*)hHi)[i] = 0; ((us*)hLo)[i] = 0; }

    const int ped = tid >> 4;
    const int prr = (tid & 15) * 4;
    float4 cst = make_float4(0.f, 0.f, 0.f, 0.f);

    const int eMF = min(e0 + ml, E_ - 1);
    const int gb  = w * 64 + q * 4;

    ushort4 gcur[4], gnxt[4];
    {
        const int tt0 = revd ? (T_ - 1) : 0;
        const us* gp = G + ((size_t)tt0 * E_ + eMF) * 256 + gb;
        #pragma unroll
        for (int mt = 0; mt < 4; ++mt) gcur[mt] = *(const ushort4*)(gp + mt * 16);
    }
    __syncthreads();

    for (int s = 0; s < T_; ++s) {
        const int tt = revd ? (T_ - 1 - s) : s;
        {
            const int sn = (s + 1 < T_) ? s + 1 : s;
            const int tn = revd ? (T_ - 1 - sn) : sn;
            const us* gp = G + ((size_t)tn * E_ + eMF) * 256 + gb;
            #pragma unroll
            for (int mt = 0; mt < 4; ++mt) gnxt[mt] = *(const ushort4*)(gp + mt * 16);
        }
        short8 bh[2], bl[2];
        #pragma unroll
        for (int ks = 0; ks < 2; ++ks) {
            bh[ks] = *(const short8*)(&hHi[ml][ks * 32 + q * 8]);
            bl[ks] = *(const short8*)(&hLo[ml][ks * 32 + q * 8]);
        }
        #pragma unroll
        for (int mt = 0; mt < 4; ++mt) {
            f32x4 acc;
            acc[0] = bf2f(gcur[mt].x); acc[1] = bf2f(gcur[mt].y);
            acc[2] = bf2f(gcur[mt].z); acc[3] = bf2f(gcur[mt].w);
            #pragma unroll
            for (int ks = 0; ks < 2; ++ks) {
                acc = __builtin_amdgcn_mfma_f32_16x16x32_bf16(wfh[mt][ks], bh[ks], acc, 0, 0, 0);
                acc = __builtin_amdgcn_mfma_f32_16x16x32_bf16(wfh[mt][ks], bl[ks], acc, 0, 0, 0);
                acc = __builtin_amdgcn_mfma_f32_16x16x32_bf16(wfl[mt][ks], bh[ks], acc, 0, 0, 0);
            }
            *(f32x4*)(&g_s[w][ml][mt * 16 + q * 4]) = acc;
        }
        __syncthreads();
        {
            const float4 gi = *(const float4*)&g_s[0][ped][prr];
            const float4 gf = *(const float4*)&g_s[1][ped][prr];
            const float4 gg = *(const float4*)&g_s[2][ped][prr];
            const float4 go = *(const float4*)&g_s[3][ped][prr];
            float4 hv;
            cst.x = sig_f(gf.x)*cst.x + sig_f(gi.x)*tanh_f(gg.x); hv.x = sig_f(go.x)*tanh_f(cst.x);
            cst.y = sig_f(gf.y)*cst.y + sig_f(gi.y)*tanh_f(gg.y); hv.y = sig_f(go.y)*tanh_f(cst.y);
            cst.z = sig_f(gf.z)*cst.z + sig_f(gi.z)*tanh_f(gg.z); hv.z = sig_f(go.z)*tanh_f(cst.z);
            cst.w = sig_f(gf.w)*cst.w + sig_f(gi.w)*tanh_f(gg.w); hv.w = sig_f(go.w)*tanh_f(cst.w);
            ushort4 hh4, hl4;
            hh4.x = f2bf(hv.x); hl4.x = f2bf(hv.x - bf2f(hh4.x));
            hh4.y = f2bf(hv.y); hl4.y = f2bf(hv.y - bf2f(hh4.y));
            hh4.z = f2bf(hv.z); hl4.z = f2bf(hv.z - bf2f(hh4.z));
            hh4.w = f2bf(hv.w); hl4.w = f2bf(hv.w - bf2f(hh4.w));
            *(ushort4*)(&hHi[ped][prr]) = hh4;
            *(ushort4*)(&hLo[ped][prr]) = hl4;
            if (e0 + ped < E_)
                *(float4*)(&hs[((size_t)tt * E_ + e0 + ped) * 64 + prr]) = hv;
        }
        __syncthreads();
        #pragma unroll
        for (int mt = 0; mt < 4; ++mt) gcur[mt] = gnxt[mt];
    }
}

__global__ __launch_bounds__(256)
void out_kernel(const float* __restrict__ hsF, const float* __restrict__ hsR,
                const float* __restrict__ priW, const float* __restrict__ prib,
                const float* __restrict__ encW, const float* __restrict__ encb,
                float* __restrict__ out)
{
    const int idx = blockIdx.x * 256 + threadIdx.x;
    const float* f = hsF + (size_t)idx * 64;
    const float* r = hsR + (size_t)idx * 64;
    float p0 = prib[0], p1 = prib[1], q0 = encb[0], q1 = encb[1];
    #pragma unroll
    for (int k4 = 0; k4 < 16; ++k4) {
        const float4 fv = *(const float4*)(f + k4 * 4);
        const float4 rv = *(const float4*)(r + k4 * 4);
        p0 += dot4(fv, *(const float4*)(priW + k4 * 4));
        p1 += dot4(fv, *(const float4*)(priW + 64 + k4 * 4));
        q0 += dot4(fv, *(const float4*)(encW + k4 * 4))
            + dot4(rv, *(const float4*)(encW + 64 + k4 * 4));
        q1 += dot4(fv, *(const float4*)(encW + 128 + k4 * 4))
            + dot4(rv, *(const float4*)(encW + 192 + k4 * 4));
    }
    float4 o; o.x = p0; o.y = p1; o.z = q0; o.w = q1;
    *(float4*)(out + (size_t)idx * 4) = o;
}

extern "C" void kernel_launch(void* const* d_in, const int* in_sizes, int n_in,
                              void* d_out, int out_size, void* d_ws, size_t ws_size,
                              hipStream_t stream)
{
    const float* x    = (const float*)d_in[0];
    const int*   send = (const int*)d_in[2];
    const int*   recv = (const int*)d_in[3];
    const float* m1W1 = (const float*)d_in[4];  const float* m1b1 = (const float*)d_in[5];
    const float* m1W2 = (const float*)d_in[6];  const float* m1b2 = (const float*)d_in[7];
    const float* m2W1 = (const float*)d_in[8];  const float* m2b1 = (const float*)d_in[9];
    const float* m2W2 = (const float*)d_in[10]; const float* m2b2 = (const float*)d_in[11];
    const float* m3W1 = (const float*)d_in[12]; const float* m3b1 = (const float*)d_in[13];
    const float* m3W2 = (const float*)d_in[14]; const float* m3b2 = (const float*)d_in[15];
    const float* m4W1 = (const float*)d_in[16]; const float* m4b1 = (const float*)d_in[17];
    const float* m4W2 = (const float*)d_in[18]; const float* m4b2 = (const float*)d_in[19];
    const float* fWih = (const float*)d_in[20]; const float* fWhh = (const float*)d_in[21];
    const float* fbih = (const float*)d_in[22]; const float* fbhh = (const float*)d_in[23];
    const float* rWih = (const float*)d_in[24]; const float* rWhh = (const float*)d_in[25];
    const float* rbih = (const float*)d_in[26]; const float* rbhh = (const float*)d_in[27];
    const float* encW = (const float*)d_in[28]; const float* encb = (const float*)d_in[29];
    const float* priW = (const float*)d_in[30]; const float* prib = (const float*)d_in[31];

    const size_t SZN  = (size_t)TN_ * H_;
    const size_t SZE  = (size_t)TE_ * H_;
    float* n_agg = (float*)d_ws;
    float* m3t   = n_agg + SZN;
    us* h16      = (us*)(m3t + SZN);
    us* n3       = h16 + SZN;
    us* w2aH = n3  + SZN;          us* w2aL = w2aH + 256*512;
    us* w2bH = w2aL + 256*512;     us* w2bL = w2bH + 256*256;
    us* w4aH = w2bL + 256*256;     us* w4aL = w4aH + 256*768;
    us* w4bH = w4aL + 256*768;     us* w4bL = w4bH + 256*256;
    us* wfiH = w4bL + 256*256;     us* wfiL = wfiH + 256*256;
    us* wriH = wfiL + 256*256;     us* wriL = wriH + 256*256;
    us* whfH = wriL + 256*256;     us* whfL = whfH + 256*64;
    us* whrH = whfL + 256*64;      us* whrL = whrH + 256*64;
    us* bufA16 = whrL + 256*64;
    us* bufB16 = bufA16 + SZE;
    us* bufC16 = bufB16 + SZE;
    float* hsF = (float*)bufC16;
    float* hsR = hsF + (size_t)TE_ * R_;
    const size_t needed = ((size_t)(bufC16 + SZE) - (size_t)d_ws);
    if (ws_size < needed) return;

    const dim3 gMF(TE_ / 128, 2), gN(TN_ / 64, 4);

    wsplit_all<<<2432, 256, 0, stream>>>(m2W1, w2aH, w2aL, m2W2, w2bH, w2bL,
                                         m4W1, w4aH, w4aL, m4W2, w4bH, w4bL,
                                         fWih, wfiH, wfiL, rWih, wriH, wriL,
                                         fWhh, whfH, whfL, rWhh, whrH, whrL);

    mlp1_kernel<<<TN_ / 8, 256, 0, stream>>>(x, m1W1, m1b1, m1W2, m1b2, h16);
    gemm_mfma<1, true><<<gMF, 256, 0, stream>>>(h16, h16, nullptr, w2aH, w2aL, m2b1, nullptr, send, recv, bufA16, 512);
    gemm_mfma<0, true><<<gMF, 256, 0, stream>>>(bufA16, nullptr, nullptr, w2bH, w2bL, m2b2, nullptr, send, recv, bufB16, 256);
    aggregate_kernel<<<TN_, 256, 0, stream>>>(bufB16, recv, n_agg);
    gemm_nt<true, float, float><<<gN, 256, 0, stream>>>(n_agg, m3W1, m3b1, m3t, TN_, 256);
    gemm_nt<true, float, us><<<gN, 256, 0, stream>>>(m3t, m3W2, m3b2, n3, TN_, 256);
    gemm_mfma<2, true><<<gMF, 256, 0, stream>>>(n3, n3, bufB16, w4aH, w4aL, m4b1, nullptr, send, recv, bufA16, 768);
    gemm_mfma<0, true><<<gMF, 256, 0, stream>>>(bufA16, nullptr, nullptr, w4bH, w4bL, m4b2, nullptr, send, recv, bufC16, 256);
    gemm_mfma<0, false><<<gMF, 256, 0, stream>>>(bufC16, nullptr, nullptr, wfiH, wfiL, fbih, fbhh, send, recv, bufA16, 256);
    gemm_mfma<0, false><<<gMF, 256, 0, stream>>>(bufC16, nullptr, nullptr, wriH, wriL, rbih, rbhh, send, recv, bufB16, 256);
    lstm_mfma<<<2 * ((E_ + 15) / 16), 256, 0, stream>>>(bufA16, bufB16, whfH, whfL, whrH, whrL, hsF, hsR);
    out_kernel<<<TE_ / 256, 256, 0, stream>>>(hsF, hsR, priW, prib, encW, encb, (float*)d_out);
}

// Round 8
// 816.959 us; speedup vs baseline: 2.7052x; 1.0279x over previous
//
#include <hip/hip_runtime.h>
#include <math.h>

#define T_ 64
#define N_ 40
#define D_ 4
#define H_ 256
#define R_ 64
#define E_ 1560
#define TE_ (T_*E_)
#define TN_ (T_*N_)

typedef unsigned short us;
typedef short short8 __attribute__((ext_vector_type(8)));
typedef float f32x4 __attribute__((ext_vector_type(4)));

__device__ __forceinline__ float elu_f(float x){ return x > 0.f ? x : (__expf(x) - 1.f); }
__device__ __forceinline__ float sig_f(float x){ return 1.f/(1.f+__expf(-x)); }
__device__ __forceinline__ float tanh_f(float x){ return 2.f/(1.f+__expf(-2.f*x)) - 1.f; }
__device__ __forceinline__ float dot4(float4 a, float4 b){ return a.x*b.x + a.y*b.y + a.z*b.z + a.w*b.w; }

__device__ __forceinline__ float bf2f(us u){ return __uint_as_float(((unsigned int)u) << 16); }
__device__ __forceinline__ us f2bf(float f){
    unsigned int u = __float_as_uint(f);
    u += 0x7FFFu + ((u >> 16) & 1u);
    return (us)(u >> 16);
}
__device__ __forceinline__ float4 ld4f(const float* p){ return *(const float4*)p; }
__device__ __forceinline__ float4 ld4f(const us* p){
    ushort4 v = *(const ushort4*)p;
    return make_float4(bf2f(v.x), bf2f(v.y), bf2f(v.z), bf2f(v.w));
}
__device__ __forceinline__ void st4f(float* p, float4 v){ *(float4*)p = v; }
__device__ __forceinline__ void st4f(us* p, float4 v){
    ushort4 o; o.x = f2bf(v.x); o.y = f2bf(v.y); o.z = f2bf(v.z); o.w = f2bf(v.w);
    *(ushort4*)p = o;
}

__device__ __forceinline__ void gld16(void* lds, const void* g){
    __builtin_amdgcn_global_load_lds((const __attribute__((address_space(1))) unsigned int*)g,
                                     (__attribute__((address_space(3))) unsigned int*)lds,
                                     16, 0, 0);
}

__device__ __forceinline__ void wsplit1(const float* W, us* hi, us* lo, int i){
    const float w = W[i];
    const us h = f2bf(w);
    hi[i] = h;
    lo[i] = f2bf(w - bf2f(h));
}

__global__ __launch_bounds__(256)
void wsplit_all(const float* __restrict__ s0, us* h0, us* l0,
                const float* __restrict__ s1, us* h1, us* l1,
                const float* __restrict__ s2, us* h2, us* l2,
                const float* __restrict__ s3, us* h3, us* l3,
                const float* __restrict__ s4, us* h4, us* l4,
                const float* __restrict__ s5, us* h5, us* l5,
                const float* __restrict__ s6, us* h6, us* l6,
                const float* __restrict__ s7, us* h7, us* l7)
{
    int i = blockIdx.x * 256 + threadIdx.x;
    if (i < 131072) { wsplit1(s0, h0, l0, i); return; } i -= 131072;
    if (i <  65536) { wsplit1(s1, h1, l1, i); return; } i -=  65536;
    if (i < 196608) { wsplit1(s2, h2, l2, i); return; } i -= 196608;
    if (i <  65536) { wsplit1(s3, h3, l3, i); return; } i -=  65536;
    if (i <  65536) { wsplit1(s4, h4, l4, i); return; } i -=  65536;
    if (i <  65536) { wsplit1(s5, h5, l5, i); return; } i -=  65536;
    if (i <  16384) { wsplit1(s6, h6, l6, i); return; } i -=  16384;
    wsplit1(s7, h7, l7, i);
}

__global__ __launch_bounds__(256)
void mlp1_kernel(const float* __restrict__ x,
                 const float* __restrict__ W1, const float* __restrict__ b1,
                 const float* __restrict__ W2, const float* __restrict__ b2,
                 us* __restrict__ hout)
{
    __shared__ float xs[8][4];
    __shared__ float h1[8][256];
    const int tid = threadIdx.x;
    const int r0  = blockIdx.x * 8;

    if (tid < 32) xs[tid >> 2][tid & 3] = x[r0 * 4 + tid];
    __syncthreads();

    const float4 w1 = *(const float4*)&W1[tid * 4];
    const float bb1 = b1[tid];
    #pragma unroll
    for (int row = 0; row < 8; ++row) {
        float v = bb1 + xs[row][0]*w1.x + xs[row][1]*w1.y + xs[row][2]*w1.z + xs[row][3]*w1.w;
        h1[row][tid] = elu_f(v);
    }
    __syncthreads();

    float acc[8];
    const float bb2 = b2[tid];
    #pragma unroll
    for (int row = 0; row < 8; ++row) acc[row] = bb2;
    const float* w2row = W2 + (size_t)tid * 256;
    for (int k4 = 0; k4 < 64; ++k4) {
        const float4 w = *(const float4*)&w2row[k4 * 4];
        #pragma unroll
        for (int row = 0; row < 8; ++row) {
            const float4 hh = *(const float4*)&h1[row][k4 * 4];
            acc[row] += dot4(hh, w);
        }
    }
    #pragma unroll
    for (int row = 0; row < 8; ++row)
        hout[(size_t)(r0 + row) * 256 + tid] = f2bf(elu_f(acc[row]));
}

// MFMA NT GEMM, double-buffered LDS + async prefetch (vmcnt(6), raw barriers).
template<int MODE, bool DOELU>
__global__ __launch_bounds__(256)
void gemm_mfma(const us* __restrict__ A, const us* __restrict__ A2, const us* __restrict__ A3,
               const us* __restrict__ Whi, const us* __restrict__ Wlo,
               const float* __restrict__ bias1, const float* __restrict__ bias2,
               const int* __restrict__ send, const int* __restrict__ recv,
               us* __restrict__ C, int Kdim)
{
    __shared__ char smem[49152];   // 2 x (8KB A + 8KB Whi + 8KB Wlo)

    const int tid  = threadIdx.x;
    const int lane = tid & 63;
    const int w    = tid >> 6;
    const int ml   = lane & 15;
    const int q    = lane >> 4;
    const int bx   = blockIdx.x;
    const int by   = blockIdx.y;
    const int eh   = w >> 1;
    const int fh   = w & 1;

    const int gr0 = bx * 128 + lane, gr1 = gr0 + 64;
    const us *pA0a=nullptr,*pA1a=nullptr,*pA2a=nullptr;
    const us *pA0b=nullptr,*pA1b=nullptr,*pA2b=nullptr;
    if (MODE == 0) {
        pA0a = A + (size_t)gr0 * Kdim;
        pA0b = A + (size_t)gr1 * Kdim;
    } else {
        const int t0 = gr0 / E_, e0 = gr0 - t0 * E_;
        const int t1 = gr1 / E_, e1 = gr1 - t1 * E_;
        pA0a = A  + ((size_t)(t0 * N_ + send[e0])) * H_;
        pA1a = A2 + ((size_t)(t0 * N_ + recv[e0])) * H_;
        pA0b = A  + ((size_t)(t1 * N_ + send[e1])) * H_;
        pA1b = A2 + ((size_t)(t1 * N_ + recv[e1])) * H_;
        if (MODE == 2) { pA2a = A3 + (size_t)gr0 * H_; pA2b = A3 + (size_t)gr1 * H_; }
    }
    const us* pWh0 = Whi + (size_t)(by * 128 + lane)      * Kdim;
    const us* pWh1 = Whi + (size_t)(by * 128 + 64 + lane) * Kdim;
    const us* pWl0 = Wlo + (size_t)(by * 128 + lane)      * Kdim;
    const us* pWl1 = Wlo + (size_t)(by * 128 + 64 + lane) * Kdim;

    f32x4 acc[4][4];
    #pragma unroll
    for (int i = 0; i < 4; ++i)
        #pragma unroll
        for (int j = 0; j < 4; ++j)
            acc[i][j] = (f32x4){0.f, 0.f, 0.f, 0.f};

    auto stage = [&](int k0, char* base) {
        const int kk = k0 + w * 8;
        const us *sa, *sb;
        if (MODE == 0) { sa = pA0a + kk; sb = pA0b + kk; }
        else if (MODE == 1) {
            sa = (kk < 256) ? pA0a + kk : pA1a + (kk - 256);
            sb = (kk < 256) ? pA0b + kk : pA1b + (kk - 256);
        } else {
            sa = (kk < 256) ? pA0a + kk : (kk < 512) ? pA1a + (kk - 256) : pA2a + (kk - 512);
            sb = (kk < 256) ? pA0b + kk : (kk < 512) ? pA1b + (kk - 256) : pA2b + (kk - 512);
        }
        gld16(base + w * 2048,                sa);
        gld16(base + w * 2048 + 1024,         sb);
        gld16(base + 8192  + w * 2048,        pWh0 + kk);
        gld16(base + 8192  + w * 2048 + 1024, pWh1 + kk);
        gld16(base + 16384 + w * 2048,        pWl0 + kk);
        gld16(base + 16384 + w * 2048 + 1024, pWl1 + kk);
    };

    stage(0, smem);
    const int nk = Kdim >> 5;
    for (int k = 0; k < nk; ++k) {
        char* cur = smem + (k & 1) * 24576;
        char* nxt = smem + ((k + 1) & 1) * 24576;
        __builtin_amdgcn_s_barrier();            // nxt's previous tile fully consumed
        if (k + 1 < nk) {
            stage((k + 1) * 32, nxt);            // prefetch: 6 newer DMAs in flight
            __builtin_amdgcn_s_waitcnt(0x3F76);  // vmcnt(6): oldest 6 (tile k) landed
        } else {
            __builtin_amdgcn_s_waitcnt(0x3F70);  // vmcnt(0)
        }
        __builtin_amdgcn_s_barrier();            // all waves' tile k visible

        short8 wh[4], wl[4], ef[4];
        #pragma unroll
        for (int mt = 0; mt < 4; ++mt) {
            const int fr = fh * 64 + mt * 16 + ml;
            wh[mt] = *(const short8*)(cur + 8192  + q * 2048 + fr * 16);
            wl[mt] = *(const short8*)(cur + 16384 + q * 2048 + fr * 16);
        }
        #pragma unroll
        for (int nt = 0; nt < 4; ++nt) {
            const int er = eh * 64 + nt * 16 + ml;
            ef[nt] = *(const short8*)(cur + q * 2048 + er * 16);
        }
        #pragma unroll
        for (int mt = 0; mt < 4; ++mt)
            #pragma unroll
            for (int nt = 0; nt < 4; ++nt) {
                acc[mt][nt] = __builtin_amdgcn_mfma_f32_16x16x32_bf16(wh[mt], ef[nt], acc[mt][nt], 0, 0, 0);
                acc[mt][nt] = __builtin_amdgcn_mfma_f32_16x16x32_bf16(wl[mt], ef[nt], acc[mt][nt], 0, 0, 0);
            }
    }

    #pragma unroll
    for (int mt = 0; mt < 4; ++mt) {
        const int colb = by * 128 + fh * 64 + mt * 16 + q * 4;
        float4 bb = *(const float4*)(bias1 + colb);
        if (bias2) {
            const float4 b2 = *(const float4*)(bias2 + colb);
            bb.x += b2.x; bb.y += b2.y; bb.z += b2.z; bb.w += b2.w;
        }
        #pragma unroll
        for (int nt = 0; nt < 4; ++nt) {
            const int row = bx * 128 + eh * 64 + nt * 16 + ml;
            float4 v;
            v.x = acc[mt][nt][0] + bb.x; v.y = acc[mt][nt][1] + bb.y;
            v.z = acc[mt][nt][2] + bb.z; v.w = acc[mt][nt][3] + bb.w;
            if (DOELU) { v.x = elu_f(v.x); v.y = elu_f(v.y); v.z = elu_f(v.z); v.w = elu_f(v.w); }
            ushort4 o; o.x = f2bf(v.x); o.y = f2bf(v.y); o.z = f2bf(v.z); o.w = f2bf(v.w);
            *(ushort4*)(C + (size_t)row * 256 + colb) = o;
        }
    }
}

template<bool DOELU, typename TA, typename TC>
__global__ __launch_bounds__(256)
void gemm_nt(const TA* __restrict__ A, const float* __restrict__ W,
             const float* __restrict__ bias1,
             TC* __restrict__ C, int M, int Kdim)
{
    __shared__ float As[16][64];
    __shared__ float Ws[16][64];

    const int tid = threadIdx.x;
    const int am  = tid >> 2;
    const int ak  = (tid & 3) * 4;
    const int gm  = blockIdx.x * 64 + am;

    const TA* aptr0 = A + (size_t)gm * Kdim;
    const float* wptr = W + (size_t)(blockIdx.y * 64 + am) * Kdim;

    const int tx = tid & 15, ty = tid >> 4;
    float acc[4][4] = {};

    for (int k0 = 0; k0 < Kdim; k0 += 16) {
        const float4 a4 = ld4f(aptr0 + k0 + ak);
        const float4 w4 = *(const float4*)(wptr + k0 + (tid & 3) * 4);

        __syncthreads();
        As[ak+0][am] = a4.x; As[ak+1][am] = a4.y; As[ak+2][am] = a4.z; As[ak+3][am] = a4.w;
        const int wk = (tid & 3) * 4;
        Ws[wk+0][am] = w4.x; Ws[wk+1][am] = w4.y; Ws[wk+2][am] = w4.z; Ws[wk+3][am] = w4.w;
        __syncthreads();

        #pragma unroll
        for (int kq = 0; kq < 16; ++kq) {
            const float4 av = *(const float4*)&As[kq][ty * 4];
            const float4 wv = *(const float4*)&Ws[kq][tx * 4];
            const float a_[4] = {av.x, av.y, av.z, av.w};
            const float w_[4] = {wv.x, wv.y, wv.z, wv.w};
            #pragma unroll
            for (int i = 0; i < 4; ++i)
                #pragma unroll
                for (int j = 0; j < 4; ++j)
                    acc[i][j] += a_[i] * w_[j];
        }
    }

    const int gn = blockIdx.y * 64 + tx * 4;
    const float4 bb = *(const float4*)&bias1[gn];
    #pragma unroll
    for (int i = 0; i < 4; ++i) {
        const int row = blockIdx.x * 64 + ty * 4 + i;
        float4 o;
        o.x = acc[i][0] + bb.x; o.y = acc[i][1] + bb.y;
        o.z = acc[i][2] + bb.z; o.w = acc[i][3] + bb.w;
        if (DOELU) { o.x = elu_f(o.x); o.y = elu_f(o.y); o.z = elu_f(o.z); o.w = elu_f(o.w); }
        st4f(C + (size_t)row * 256 + gn, o);
    }
}

__global__ __launch_bounds__(256)
void aggregate_kernel(const us* __restrict__ eSkip, const int* __restrict__ recv,
                      float* __restrict__ nAgg)
{
    const int t = blockIdx.x / N_;
    const int j = blockIdx.x - t * N_;
    const int c = threadIdx.x;
    const us* basep = eSkip + (size_t)t * E_ * H_;
    float acc = 0.f;
    for (int e = 0; e < E_; ++e) {
        if (recv[e] == j) acc += bf2f(basep[(size_t)e * H_ + c]);
    }
    nAgg[(size_t)blockIdx.x * H_ + c] = acc;
}

// LSTM recurrence v3: MFMA recurrent GEMM (unchanged from round 7).
__global__ __launch_bounds__(256)
void lstm_mfma(const us* __restrict__ Gf, const us* __restrict__ Gr,
               const us* __restrict__ fWhhH, const us* __restrict__ fWhhL,
               const us* __restrict__ rWhhH, const us* __restrict__ rWhhL,
               float* __restrict__ hsF, float* __restrict__ hsR)
{
    const int NBD = (E_ + 15) / 16;
    const bool revd = (int)blockIdx.x >= NBD;
    const int blk = revd ? (int)blockIdx.x - NBD : (int)blockIdx.x;
    const int e0 = blk * 16;
    const us* G  = revd ? Gr : Gf;
    const us* WH = revd ? rWhhH : fWhhH;
    const us* WL = revd ? rWhhL : fWhhL;
    float* hs    = revd ? hsR : hsF;

    const int tid  = threadIdx.x;
    const int lane = tid & 63;
    const int w    = tid >> 6;
    const int ml   = lane & 15;
    const int q    = lane >> 4;

    __shared__ float g_s[4][16][68];
    __shared__ us hHi[16][72];
    __shared__ us hLo[16][72];

    short8 wfh[4][2], wfl[4][2];
    #pragma unroll
    for (int mt = 0; mt < 4; ++mt) {
        const int row = w * 64 + mt * 16 + ml;
        #pragma unroll
        for (int ks = 0; ks < 2; ++ks) {
            wfh[mt][ks] = *(const short8*)(WH + (size_t)row * 64 + ks * 32 + q * 8);
            wfl[mt][ks] = *(const short8*)(WL + (size_t)row * 64 + ks * 32 + q * 8);
        }
    }

    for (int i = tid; i < 16 * 72; i += 256) { ((us*)hHi)[i] = 0; ((us*)hLo)[i] = 0; }

    const int ped = tid >> 4;
    const int prr = (tid & 15) * 4;
    float4 cst = make_float4(0.f, 0.f, 0.f, 0.f);

    const int eMF = min(e0 + ml, E_ - 1);
    const int gb  = w * 64 + q * 4;

    ushort4 gcur[4], gnxt[4];
    {
        const int tt0 = revd ? (T_ - 1) : 0;
        const us* gp = G + ((size_t)tt0 * E_ + eMF) * 256 + gb;
        #pragma unroll
        for (int mt = 0; mt < 4; ++mt) gcur[mt] = *(const ushort4*)(gp + mt * 16);
    }
    __syncthreads();

    for (int s = 0; s < T_; ++s) {
        const int tt = revd ? (T_ - 1 - s) : s;
        {
            const int sn = (s + 1 < T_) ? s + 1 : s;
            const int tn = revd ? (T_ - 1 - sn) : sn;
            const us* gp = G + ((size_t)tn * E_ + eMF) * 256 + gb;
            #pragma unroll
            for (int mt = 0; mt < 4; ++mt) gnxt[mt] = *(const ushort4*)(gp + mt * 16);
        }
        short8 bh[2], bl[2];
        #pragma unroll
        for (int ks = 0; ks < 2; ++ks) {
            bh[ks] = *(const short8*)(&hHi[ml][ks * 32 + q * 8]);
            bl[ks] = *(const short8*)(&hLo[ml][ks * 32 + q * 8]);
        }
        #pragma unroll
        for (int mt = 0; mt < 4; ++mt) {
            f32x4 acc;
            acc[0] = bf2f(gcur[mt].x); acc[1] = bf2f(gcur[mt].y);
            acc[2] = bf2f(gcur[mt].z); acc[3] = bf2f(gcur[mt].w);
            #pragma unroll
            for (int ks = 0; ks < 2; ++ks) {
                acc = __builtin_amdgcn_mfma_f32_16x16x32_bf16(wfh[mt][ks], bh[ks], acc, 0, 0, 0);
                acc = __builtin_amdgcn_mfma_f32_16x16x32_bf16(wfh[mt][ks], bl[ks], acc, 0, 0, 0);
                acc = __builtin_amdgcn_mfma_f32_16x16x32_bf16(wfl[mt][ks], bh[ks], acc, 0, 0, 0);
            }
            *(f32x4*)(&g_s[w][ml][mt * 16 + q * 4]) = acc;
        }
        __syncthreads();
        {
            const float4 gi = *(const float4*)&g_s[0][ped][prr];
            const float4 gf = *(const float4*)&g_s[1][ped][prr];
            const float4 gg = *(const float4*)&g_s[2][ped][prr];
            const float4 go = *(const float4*)&g_s[3][ped][prr];
            float4 hv;
            cst.x = sig_f(gf.x)*cst.x + sig_f(gi.x)*tanh_f(gg.x); hv.x = sig_f(go.x)*tanh_f(cst.x);
            cst.y = sig_f(gf.y)*cst.y + sig_f(gi.y)*tanh_f(gg.y); hv.y = sig_f(go.y)*tanh_f(cst.y);
            cst.z = sig_f(gf.z)*cst.z + sig_f(gi.z)*tanh_f(gg.z); hv.z = sig_f(go.z)*tanh_f(cst.z);
            cst.w = sig_f(gf.w)*cst.w + sig_f(gi.w)*tanh_f(gg.w); hv.w = sig_f(go.w)*tanh_f(cst.w);
            ushort4 hh4, hl4;
            hh4.x = f2bf(hv.x); hl4.x = f2bf(hv.x - bf2f(hh4.x));
            hh4.y = f2bf(hv.y); hl4.y = f2bf(hv.y - bf2f(hh4.y));
            hh4.z = f2bf(hv.z); hl4.z = f2bf(hv.z - bf2f(hh4.z));
            hh4.w = f2bf(hv.w); hl4.w = f2bf(hv.w - bf2f(hh4.w));
            *(ushort4*)(&hHi[ped][prr]) = hh4;
            *(ushort4*)(&hLo[ped][prr]) = hl4;
            if (e0 + ped < E_)
                *(float4*)(&hs[((size_t)tt * E_ + e0 + ped) * 64 + prr]) = hv;
        }
        __syncthreads();
        #pragma unroll
        for (int mt = 0; mt < 4; ++mt) gcur[mt] = gnxt[mt];
    }
}

__global__ __launch_bounds__(256)
void out_kernel(const float* __restrict__ hsF, const float* __restrict__ hsR,
                const float* __restrict__ priW, const float* __restrict__ prib,
                const float* __restrict__ encW, const float* __restrict__ encb,
                float* __restrict__ out)
{
    const int idx = blockIdx.x * 256 + threadIdx.x;
    const float* f = hsF + (size_t)idx * 64;
    const float* r = hsR + (size_t)idx * 64;
    float p0 = prib[0], p1 = prib[1], q0 = encb[0], q1 = encb[1];
    #pragma unroll
    for (int k4 = 0; k4 < 16; ++k4) {
        const float4 fv = *(const float4*)(f + k4 * 4);
        const float4 rv = *(const float4*)(r + k4 * 4);
        p0 += dot4(fv, *(const float4*)(priW + k4 * 4));
        p1 += dot4(fv, *(const float4*)(priW + 64 + k4 * 4));
        q0 += dot4(fv, *(const float4*)(encW + k4 * 4))
            + dot4(rv, *(const float4*)(encW + 64 + k4 * 4));
        q1 += dot4(fv, *(const float4*)(encW + 128 + k4 * 4))
            + dot4(rv, *(const float4*)(encW + 192 + k4 * 4));
    }
    float4 o; o.x = p0; o.y = p1; o.z = q0; o.w = q1;
    *(float4*)(out + (size_t)idx * 4) = o;
}

extern "C" void kernel_launch(void* const* d_in, const int* in_sizes, int n_in,
                              void* d_out, int out_size, void* d_ws, size_t ws_size,
                              hipStream_t stream)
{
    const float* x    = (const float*)d_in[0];
    const int*   send = (const int*)d_in[2];
    const int*   recv = (const int*)d_in[3];
    const float* m1W1 = (const float*)d_in[4];  const float* m1b1 = (const float*)d_in[5];
    const float* m1W2 = (const float*)d_in[6];  const float* m1b2 = (const float*)d_in[7];
    const float* m2W1 = (const float*)d_in[8];  const float* m2b1 = (const float*)d_in[9];
    const float* m2W2 = (const float*)d_in[10]; const float* m2b2 = (const float*)d_in[11];
    const float* m3W1 = (const float*)d_in[12]; const float* m3b1 = (const float*)d_in[13];
    const float* m3W2 = (const float*)d_in[14]; const float* m3b2 = (const float*)d_in[15];
    const float* m4W1 = (const float*)d_in[16]; const float* m4b1 = (const float*)d_in[17];
    const float* m4W2 = (const float*)d_in[18]; const float* m4b2 = (const float*)d_in[19];
    const float* fWih = (const float*)d_in[20]; const float* fWhh = (const float*)d_in[21];
    const float* fbih = (const float*)d_in[22]; const float* fbhh = (const float*)d_in[23];
    const float* rWih = (const float*)d_in[24]; const float* rWhh = (const float*)d_in[25];
    const float* rbih = (const float*)d_in[26]; const float* rbhh = (const float*)d_in[27];
    const float* encW = (const float*)d_in[28]; const float* encb = (const float*)d_in[29];
    const float* priW = (const float*)d_in[30]; const float* prib = (const float*)d_in[31];

    const size_t SZN  = (size_t)TN_ * H_;
    const size_t SZE  = (size_t)TE_ * H_;
    float* n_agg = (float*)d_ws;
    float* m3t   = n_agg + SZN;
    us* h16      = (us*)(m3t + SZN);
    us* n3       = h16 + SZN;
    us* w2aH = n3  + SZN;          us* w2aL = w2aH + 256*512;
    us* w2bH = w2aL + 256*512;     us* w2bL = w2bH + 256*256;
    us* w4aH = w2bL + 256*256;     us* w4aL = w4aH + 256*768;
    us* w4bH = w4aL + 256*768;     us* w4bL = w4bH + 256*256;
    us* wfiH = w4bL + 256*256;     us* wfiL = wfiH + 256*256;
    us* wriH = wfiL + 256*256;     us* wriL = wriH + 256*256;
    us* whfH = wriL + 256*256;     us* whfL = whfH + 256*64;
    us* whrH = whfL + 256*64;      us* whrL = whrH + 256*64;
    us* bufA16 = whrL + 256*64;
    us* bufB16 = bufA16 + SZE;
    us* bufC16 = bufB16 + SZE;
    float* hsF = (float*)bufC16;
    float* hsR = hsF + (size_t)TE_ * R_;
    const size_t needed = ((size_t)(bufC16 + SZE) - (size_t)d_ws);
    if (ws_size < needed) return;

    const dim3 gMF(TE_ / 128, 2), gN(TN_ / 64, 4);

    wsplit_all<<<2432, 256, 0, stream>>>(m2W1, w2aH, w2aL, m2W2, w2bH, w2bL,
                                         m4W1, w4aH, w4aL, m4W2, w4bH, w4bL,
                                         fWih, wfiH, wfiL, rWih, wriH, wriL,
                                         fWhh, whfH, whfL, rWhh, whrH, whrL);

    mlp1_kernel<<<TN_ / 8, 256, 0, stream>>>(x, m1W1, m1b1, m1W2, m1b2, h16);
    gemm_mfma<1, true><<<gMF, 256, 0, stream>>>(h16, h16, nullptr, w2aH, w2aL, m2b1, nullptr, send, recv, bufA16, 512);
    gemm_mfma<0, true><<<gMF, 256, 0, stream>>>(bufA16, nullptr, nullptr, w2bH, w2bL, m2b2, nullptr, send, recv, bufB16, 256);
    aggregate_kernel<<<TN_, 256, 0, stream>>>(bufB16, recv, n_agg);
    gemm_nt<true, float, float><<<gN, 256, 0, stream>>>(n_agg, m3W1, m3b1, m3t, TN_, 256);
    gemm_nt<true, float, us><<<gN, 256, 0, stream>>>(m3t, m3W2, m3b2, n3, TN_, 256);
    gemm_mfma<2, true><<<gMF, 256, 0, stream>>>(n3, n3, bufB16, w4aH, w4aL, m4b1, nullptr, send, recv, bufA16, 768);
    gemm_mfma<0, true><<<gMF, 256, 0, stream>>>(bufA16, nullptr, nullptr, w4bH, w4bL, m4b2, nullptr, send, recv, bufC16, 256);
    gemm_mfma<0, false><<<gMF, 256, 0, stream>>>(bufC16, nullptr, nullptr, wfiH, wfiL, fbih, fbhh, send, recv, bufA16, 256);
    gemm_mfma<0, false><<<gMF, 256, 0, stream>>>(bufC16, nullptr, nullptr, wriH, wriL, rbih, rbhh, send, recv, bufB16, 256);
    lstm_mfma<<<2 * ((E_ + 15) / 16), 256, 0, stream>>>(bufA16, bufB16, whfH, whfL, whrH, whrL, hsF, hsR);
    out_kernel<<<TE_ / 256, 256, 0, stream>>>(hsF, hsR, priW, prib, encW, encb, (float*)d_out);
}

// Round 9
// 690.803 us; speedup vs baseline: 3.1992x; 1.1826x over previous
//
#include <hip/hip_runtime.h>
#include <math.h>

#define T_ 64
#define N_ 40
#define D_ 4
#define H_ 256
#define R_ 64
#define E_ 1560
#define TE_ (T_*E_)
#define TN_ (T_*N_)

typedef unsigned short us;
typedef short short8 __attribute__((ext_vector_type(8)));
typedef float f32x4 __attribute__((ext_vector_type(4)));

__device__ __forceinline__ float elu_f(float x){ return x > 0.f ? x : (__expf(x) - 1.f); }
__device__ __forceinline__ float sig_f(float x){ return 1.f/(1.f+__expf(-x)); }
__device__ __forceinline__ float tanh_f(float x){ return 2.f/(1.f+__expf(-2.f*x)) - 1.f; }
__device__ __forceinline__ float dot4(float4 a, float4 b){ return a.x*b.x + a.y*b.y + a.z*b.z + a.w*b.w; }

__device__ __forceinline__ float bf2f(us u){ return __uint_as_float(((unsigned int)u) << 16); }
__device__ __forceinline__ us f2bf(float f){
    unsigned int u = __float_as_uint(f);
    u += 0x7FFFu + ((u >> 16) & 1u);
    return (us)(u >> 16);
}
__device__ __forceinline__ float4 ld4f(const float* p){ return *(const float4*)p; }
__device__ __forceinline__ float4 ld4f(const us* p){
    ushort4 v = *(const ushort4*)p;
    return make_float4(bf2f(v.x), bf2f(v.y), bf2f(v.z), bf2f(v.w));
}
__device__ __forceinline__ void st4f(float* p, float4 v){ *(float4*)p = v; }
__device__ __forceinline__ void st4f(us* p, float4 v){
    ushort4 o; o.x = f2bf(v.x); o.y = f2bf(v.y); o.z = f2bf(v.z); o.w = f2bf(v.w);
    *(ushort4*)p = o;
}

__device__ __forceinline__ void gld16(void* lds, const void* g){
    __builtin_amdgcn_global_load_lds((const __attribute__((address_space(1))) unsigned int*)g,
                                     (__attribute__((address_space(3))) unsigned int*)lds,
                                     16, 0, 0);
}

__device__ __forceinline__ void wsplit1(const float* W, us* hi, us* lo, int i){
    const float w = W[i];
    const us h = f2bf(w);
    hi[i] = h;
    lo[i] = f2bf(w - bf2f(h));
}

__global__ __launch_bounds__(256)
void wsplit_all(const float* __restrict__ s0, us* h0, us* l0,
                const float* __restrict__ s1, us* h1, us* l1,
                const float* __restrict__ s2, us* h2, us* l2,
                const float* __restrict__ s3, us* h3, us* l3,
                const float* __restrict__ s4, us* h4, us* l4,
                const float* __restrict__ s5, us* h5, us* l5,
                const float* __restrict__ s6, us* h6, us* l6,
                const float* __restrict__ s7, us* h7, us* l7)
{
    int i = blockIdx.x * 256 + threadIdx.x;
    if (i < 131072) { wsplit1(s0, h0, l0, i); return; } i -= 131072;
    if (i <  65536) { wsplit1(s1, h1, l1, i); return; } i -=  65536;
    if (i < 196608) { wsplit1(s2, h2, l2, i); return; } i -= 196608;
    if (i <  65536) { wsplit1(s3, h3, l3, i); return; } i -=  65536;
    if (i <  65536) { wsplit1(s4, h4, l4, i); return; } i -=  65536;
    if (i <  65536) { wsplit1(s5, h5, l5, i); return; } i -=  65536;
    if (i <  16384) { wsplit1(s6, h6, l6, i); return; } i -=  16384;
    wsplit1(s7, h7, l7, i);
}

__global__ __launch_bounds__(256)
void mlp1_kernel(const float* __restrict__ x,
                 const float* __restrict__ W1, const float* __restrict__ b1,
                 const float* __restrict__ W2, const float* __restrict__ b2,
                 us* __restrict__ hout)
{
    __shared__ float xs[8][4];
    __shared__ float h1[8][256];
    const int tid = threadIdx.x;
    const int r0  = blockIdx.x * 8;

    if (tid < 32) xs[tid >> 2][tid & 3] = x[r0 * 4 + tid];
    __syncthreads();

    const float4 w1 = *(const float4*)&W1[tid * 4];
    const float bb1 = b1[tid];
    #pragma unroll
    for (int row = 0; row < 8; ++row) {
        float v = bb1 + xs[row][0]*w1.x + xs[row][1]*w1.y + xs[row][2]*w1.z + xs[row][3]*w1.w;
        h1[row][tid] = elu_f(v);
    }
    __syncthreads();

    float acc[8];
    const float bb2 = b2[tid];
    #pragma unroll
    for (int row = 0; row < 8; ++row) acc[row] = bb2;
    const float* w2row = W2 + (size_t)tid * 256;
    for (int k4 = 0; k4 < 64; ++k4) {
        const float4 w = *(const float4*)&w2row[k4 * 4];
        #pragma unroll
        for (int row = 0; row < 8; ++row) {
            const float4 hh = *(const float4*)&h1[row][k4 * 4];
            acc[row] += dot4(hh, w);
        }
    }
    #pragma unroll
    for (int row = 0; row < 8; ++row)
        hout[(size_t)(r0 + row) * 256 + tid] = f2bf(elu_f(acc[row]));
}

// ---------------------------------------------------------------------------
// MFMA NT GEMM, double-buffered, COALESCED staging: 4 lanes cover one row's
// contiguous 64B (BK=32 bf16) -> 16 cache lines per global_load_lds instead of
// 64 divergent 16B requests. LDS layout: row-major [128 rows][64B].
// DUAL (MODE 0 only): blockIdx.y in {2,3} uses second weight/bias/output set
// (merged forward+reverse gate GEMMs).
// ---------------------------------------------------------------------------
template<int MODE, bool DOELU>
__global__ __launch_bounds__(256)
void gemm_mfma(const us* __restrict__ A, const us* __restrict__ A2, const us* __restrict__ A3,
               const us* __restrict__ Whi, const us* __restrict__ Wlo,
               const float* __restrict__ bias1, const float* __restrict__ bias2,
               const int* __restrict__ send, const int* __restrict__ recv,
               us* __restrict__ C, int Kdim,
               const us* __restrict__ Whi2, const us* __restrict__ Wlo2,
               const float* __restrict__ bias1b, const float* __restrict__ bias2b,
               us* __restrict__ C2)
{
    __shared__ char smem[49152];   // 2 x (8KB A + 8KB Whi + 8KB Wlo)

    const int tid  = threadIdx.x;
    const int lane = tid & 63;
    const int w    = tid >> 6;
    const int ml   = lane & 15;
    const int q    = lane >> 4;
    const int bx   = blockIdx.x;
    int by         = blockIdx.y;
    const int eh   = w >> 1;
    const int fh   = w & 1;

    if (MODE == 0 && C2 != nullptr && by >= 2) {
        Whi = Whi2; Wlo = Wlo2; bias1 = bias1b; bias2 = bias2b; C = C2; by -= 2;
    }

    // staging rows for this lane: 4 lanes per row, 16B chunk (lane&3)
    const int srow0 = w * 32 + (lane >> 2);        // A/W row within tile, instr 0
    const int srow1 = srow0 + 16;                  // instr 1
    const int cofs  = (lane & 3) * 8;              // element offset within 32-elem chunk

    const int gr0 = bx * 128 + srow0, gr1 = bx * 128 + srow1;
    const us *pA0a=nullptr,*pA1a=nullptr,*pA2a=nullptr;
    const us *pA0b=nullptr,*pA1b=nullptr,*pA2b=nullptr;
    if (MODE == 0) {
        pA0a = A + (size_t)gr0 * Kdim;
        pA0b = A + (size_t)gr1 * Kdim;
    } else {
        const int t0 = gr0 / E_, e0 = gr0 - t0 * E_;
        const int t1 = gr1 / E_, e1 = gr1 - t1 * E_;
        pA0a = A  + ((size_t)(t0 * N_ + send[e0])) * H_;
        pA1a = A2 + ((size_t)(t0 * N_ + recv[e0])) * H_;
        pA0b = A  + ((size_t)(t1 * N_ + send[e1])) * H_;
        pA1b = A2 + ((size_t)(t1 * N_ + recv[e1])) * H_;
        if (MODE == 2) { pA2a = A3 + (size_t)gr0 * H_; pA2b = A3 + (size_t)gr1 * H_; }
    }
    const us* pWh0 = Whi + (size_t)(by * 128 + srow0) * Kdim;
    const us* pWh1 = Whi + (size_t)(by * 128 + srow1) * Kdim;
    const us* pWl0 = Wlo + (size_t)(by * 128 + srow0) * Kdim;
    const us* pWl1 = Wlo + (size_t)(by * 128 + srow1) * Kdim;

    f32x4 acc[4][4];
    #pragma unroll
    for (int i = 0; i < 4; ++i)
        #pragma unroll
        for (int j = 0; j < 4; ++j)
            acc[i][j] = (f32x4){0.f, 0.f, 0.f, 0.f};

    auto stage = [&](int k0, char* base) {
        const us *sa, *sb;
        if (MODE == 0) { sa = pA0a + k0; sb = pA0b + k0; }
        else if (MODE == 1) {
            sa = (k0 < 256) ? pA0a + k0 : pA1a + (k0 - 256);
            sb = (k0 < 256) ? pA0b + k0 : pA1b + (k0 - 256);
        } else {
            sa = (k0 < 256) ? pA0a + k0 : (k0 < 512) ? pA1a + (k0 - 256) : pA2a + (k0 - 512);
            sb = (k0 < 256) ? pA0b + k0 : (k0 < 512) ? pA1b + (k0 - 256) : pA2b + (k0 - 512);
        }
        // LDS: row-major [row][64B]; wave w instr j covers rows w*32+j*16..+15
        gld16(base + w * 2048,                sa + cofs);
        gld16(base + w * 2048 + 1024,         sb + cofs);
        gld16(base + 8192  + w * 2048,        pWh0 + k0 + cofs);
        gld16(base + 8192  + w * 2048 + 1024, pWh1 + k0 + cofs);
        gld16(base + 16384 + w * 2048,        pWl0 + k0 + cofs);
        gld16(base + 16384 + w * 2048 + 1024, pWl1 + k0 + cofs);
    };

    stage(0, smem);
    const int nk = Kdim >> 5;
    for (int k = 0; k < nk; ++k) {
        char* cur = smem + (k & 1) * 24576;
        char* nxt = smem + ((k + 1) & 1) * 24576;
        __builtin_amdgcn_s_barrier();
        if (k + 1 < nk) {
            stage((k + 1) * 32, nxt);
            __builtin_amdgcn_s_waitcnt(0x3F76);  // vmcnt(6)
        } else {
            __builtin_amdgcn_s_waitcnt(0x3F70);  // vmcnt(0)
        }
        __builtin_amdgcn_s_barrier();

        short8 wh[4], wl[4], ef[4];
        #pragma unroll
        for (int mt = 0; mt < 4; ++mt) {
            const int fr = fh * 64 + mt * 16 + ml;
            wh[mt] = *(const short8*)(cur + 8192  + fr * 64 + q * 16);
            wl[mt] = *(const short8*)(cur + 16384 + fr * 64 + q * 16);
        }
        #pragma unroll
        for (int nt = 0; nt < 4; ++nt) {
            const int er = eh * 64 + nt * 16 + ml;
            ef[nt] = *(const short8*)(cur + er * 64 + q * 16);
        }
        #pragma unroll
        for (int mt = 0; mt < 4; ++mt)
            #pragma unroll
            for (int nt = 0; nt < 4; ++nt) {
                acc[mt][nt] = __builtin_amdgcn_mfma_f32_16x16x32_bf16(wh[mt], ef[nt], acc[mt][nt], 0, 0, 0);
                acc[mt][nt] = __builtin_amdgcn_mfma_f32_16x16x32_bf16(wl[mt], ef[nt], acc[mt][nt], 0, 0, 0);
            }
    }

    #pragma unroll
    for (int mt = 0; mt < 4; ++mt) {
        const int colb = by * 128 + fh * 64 + mt * 16 + q * 4;
        float4 bb = *(const float4*)(bias1 + colb);
        if (bias2) {
            const float4 b2 = *(const float4*)(bias2 + colb);
            bb.x += b2.x; bb.y += b2.y; bb.z += b2.z; bb.w += b2.w;
        }
        #pragma unroll
        for (int nt = 0; nt < 4; ++nt) {
            const int row = bx * 128 + eh * 64 + nt * 16 + ml;
            float4 v;
            v.x = acc[mt][nt][0] + bb.x; v.y = acc[mt][nt][1] + bb.y;
            v.z = acc[mt][nt][2] + bb.z; v.w = acc[mt][nt][3] + bb.w;
            if (DOELU) { v.x = elu_f(v.x); v.y = elu_f(v.y); v.z = elu_f(v.z); v.w = elu_f(v.w); }
            ushort4 o; o.x = f2bf(v.x); o.y = f2bf(v.y); o.z = f2bf(v.z); o.w = f2bf(v.w);
            *(ushort4*)(C + (size_t)row * 256 + colb) = o;
        }
    }
}

template<bool DOELU, typename TA, typename TC>
__global__ __launch_bounds__(256)
void gemm_nt(const TA* __restrict__ A, const float* __restrict__ W,
             const float* __restrict__ bias1,
             TC* __restrict__ C, int M, int Kdim)
{
    __shared__ float As[16][64];
    __shared__ float Ws[16][64];

    const int tid = threadIdx.x;
    const int am  = tid >> 2;
    const int ak  = (tid & 3) * 4;
    const int gm  = blockIdx.x * 64 + am;

    const TA* aptr0 = A + (size_t)gm * Kdim;
    const float* wptr = W + (size_t)(blockIdx.y * 64 + am) * Kdim;

    const int tx = tid & 15, ty = tid >> 4;
    float acc[4][4] = {};

    for (int k0 = 0; k0 < Kdim; k0 += 16) {
        const float4 a4 = ld4f(aptr0 + k0 + ak);
        const float4 w4 = *(const float4*)(wptr + k0 + (tid & 3) * 4);

        __syncthreads();
        As[ak+0][am] = a4.x; As[ak+1][am] = a4.y; As[ak+2][am] = a4.z; As[ak+3][am] = a4.w;
        const int wk = (tid & 3) * 4;
        Ws[wk+0][am] = w4.x; Ws[wk+1][am] = w4.y; Ws[wk+2][am] = w4.z; Ws[wk+3][am] = w4.w;
        __syncthreads();

        #pragma unroll
        for (int kq = 0; kq < 16; ++kq) {
            const float4 av = *(const float4*)&As[kq][ty * 4];
            const float4 wv = *(const float4*)&Ws[kq][tx * 4];
            const float a_[4] = {av.x, av.y, av.z, av.w};
            const float w_[4] = {wv.x, wv.y, wv.z, wv.w};
            #pragma unroll
            for (int i = 0; i < 4; ++i)
                #pragma unroll
                for (int j = 0; j < 4; ++j)
                    acc[i][j] += a_[i] * w_[j];
        }
    }

    const int gn = blockIdx.y * 64 + tx * 4;
    const float4 bb = *(const float4*)&bias1[gn];
    #pragma unroll
    for (int i = 0; i < 4; ++i) {
        const int row = blockIdx.x * 64 + ty * 4 + i;
        float4 o;
        o.x = acc[i][0] + bb.x; o.y = acc[i][1] + bb.y;
        o.z = acc[i][2] + bb.z; o.w = acc[i][3] + bb.w;
        if (DOELU) { o.x = elu_f(o.x); o.y = elu_f(o.y); o.z = elu_f(o.z); o.w = elu_f(o.w); }
        st4f(C + (size_t)row * 256 + gn, o);
    }
}

__global__ __launch_bounds__(256)
void aggregate_kernel(const us* __restrict__ eSkip, const int* __restrict__ recv,
                      float* __restrict__ nAgg)
{
    const int t = blockIdx.x / N_;
    const int j = blockIdx.x - t * N_;
    const int c = threadIdx.x;
    const us* basep = eSkip + (size_t)t * E_ * H_;
    float acc = 0.f;
    for (int e = 0; e < E_; ++e) {
        if (recv[e] == j) acc += bf2f(basep[(size_t)e * H_ + c]);
    }
    nAgg[(size_t)blockIdx.x * H_ + c] = acc;
}

// LSTM recurrence: MFMA recurrent GEMM (unchanged).
__global__ __launch_bounds__(256)
void lstm_mfma(const us* __restrict__ Gf, const us* __restrict__ Gr,
               const us* __restrict__ fWhhH, const us* __restrict__ fWhhL,
               const us* __restrict__ rWhhH, const us* __restrict__ rWhhL,
               float* __restrict__ hsF, float* __restrict__ hsR)
{
    const int NBD = (E_ + 15) / 16;
    const bool revd = (int)blockIdx.x >= NBD;
    const int blk = revd ? (int)blockIdx.x - NBD : (int)blockIdx.x;
    const int e0 = blk * 16;
    const us* G  = revd ? Gr : Gf;
    const us* WH = revd ? rWhhH : fWhhH;
    const us* WL = revd ? rWhhL : fWhhL;
    float* hs    = revd ? hsR : hsF;

    const int tid  = threadIdx.x;
    const int lane = tid & 63;
    const int w    = tid >> 6;
    const int ml   = lane & 15;
    const int q    = lane >> 4;

    __shared__ float g_s[4][16][68];
    __shared__ us hHi[16][72];
    __shared__ us hLo[16][72];

    short8 wfh[4][2], wfl[4][2];
    #pragma unroll
    for (int mt = 0; mt < 4; ++mt) {
        const int row = w * 64 + mt * 16 + ml;
        #pragma unroll
        for (int ks = 0; ks < 2; ++ks) {
            wfh[mt][ks] = *(const short8*)(WH + (size_t)row * 64 + ks * 32 + q * 8);
            wfl[mt][ks] = *(const short8*)(WL + (size_t)row * 64 + ks * 32 + q * 8);
        }
    }

    for (int i = tid; i < 16 * 72; i += 256) { ((us*)hHi)[i] = 0; ((us*)hLo)[i] = 0; }

    const int ped = tid >> 4;
    const int prr = (tid & 15) * 4;
    float4 cst = make_float4(0.f, 0.f, 0.f, 0.f);

    const int eMF = min(e0 + ml, E_ - 1);
    const int gb  = w * 64 + q * 4;

    ushort4 gcur[4], gnxt[4];
    {
        const int tt0 = revd ? (T_ - 1) : 0;
        const us* gp = G + ((size_t)tt0 * E_ + eMF) * 256 + gb;
        #pragma unroll
        for (int mt = 0; mt < 4; ++mt) gcur[mt] = *(const ushort4*)(gp + mt * 16);
    }
    __syncthreads();

    for (int s = 0; s < T_; ++s) {
        const int tt = revd ? (T_ - 1 - s) : s;
        {
            const int sn = (s + 1 < T_) ? s + 1 : s;
            const int tn = revd ? (T_ - 1 - sn) : sn;
            const us* gp = G + ((size_t)tn * E_ + eMF) * 256 + gb;
            #pragma unroll
            for (int mt = 0; mt < 4; ++mt) gnxt[mt] = *(const ushort4*)(gp + mt * 16);
        }
        short8 bh[2], bl[2];
        #pragma unroll
        for (int ks = 0; ks < 2; ++ks) {
            bh[ks] = *(const short8*)(&hHi[ml][ks * 32 + q * 8]);
            bl[ks] = *(const short8*)(&hLo[ml][ks * 32 + q * 8]);
        }
        #pragma unroll
        for (int mt = 0; mt < 4; ++mt) {
            f32x4 acc;
            acc[0] = bf2f(gcur[mt].x); acc[1] = bf2f(gcur[mt].y);
            acc[2] = bf2f(gcur[mt].z); acc[3] = bf2f(gcur[mt].w);
            #pragma unroll
            for (int ks = 0; ks < 2; ++ks) {
                acc = __builtin_amdgcn_mfma_f32_16x16x32_bf16(wfh[mt][ks], bh[ks], acc, 0, 0, 0);
                acc = __builtin_amdgcn_mfma_f32_16x16x32_bf16(wfh[mt][ks], bl[ks], acc, 0, 0, 0);
                acc = __builtin_amdgcn_mfma_f32_16x16x32_bf16(wfl[mt][ks], bh[ks], acc, 0, 0, 0);
            }
            *(f32x4*)(&g_s[w][ml][mt * 16 + q * 4]) = acc;
        }
        __syncthreads();
        {
            const float4 gi = *(const float4*)&g_s[0][ped][prr];
            const float4 gf = *(const float4*)&g_s[1][ped][prr];
            const float4 gg = *(const float4*)&g_s[2][ped][prr];
            const float4 go = *(const float4*)&g_s[3][ped][prr];
            float4 hv;
            cst.x = sig_f(gf.x)*cst.x + sig_f(gi.x)*tanh_f(gg.x); hv.x = sig_f(go.x)*tanh_f(cst.x);
            cst.y = sig_f(gf.y)*cst.y + sig_f(gi.y)*tanh_f(gg.y); hv.y = sig_f(go.y)*tanh_f(cst.y);
            cst.z = sig_f(gf.z)*cst.z + sig_f(gi.z)*tanh_f(gg.z); hv.z = sig_f(go.z)*tanh_f(cst.z);
            cst.w = sig_f(gf.w)*cst.w + sig_f(gi.w)*tanh_f(gg.w); hv.w = sig_f(go.w)*tanh_f(cst.w);
            ushort4 hh4, hl4;
            hh4.x = f2bf(hv.x); hl4.x = f2bf(hv.x - bf2f(hh4.x));
            hh4.y = f2bf(hv.y); hl4.y = f2bf(hv.y - bf2f(hh4.y));
            hh4.z = f2bf(hv.z); hl4.z = f2bf(hv.z - bf2f(hh4.z));
            hh4.w = f2bf(hv.w); hl4.w = f2bf(hv.w - bf2f(hh4.w));
            *(ushort4*)(&hHi[ped][prr]) = hh4;
            *(ushort4*)(&hLo[ped][prr]) = hl4;
            if (e0 + ped < E_)
                *(float4*)(&hs[((size_t)tt * E_ + e0 + ped) * 64 + prr]) = hv;
        }
        __syncthreads();
        #pragma unroll
        for (int mt = 0; mt < 4; ++mt) gcur[mt] = gnxt[mt];
    }
}

__global__ __launch_bounds__(256)
void out_kernel(const float* __restrict__ hsF, const float* __restrict__ hsR,
                const float* __restrict__ priW, const float* __restrict__ prib,
                const float* __restrict__ encW, const float* __restrict__ encb,
                float* __restrict__ out)
{
    const int idx = blockIdx.x * 256 + threadIdx.x;
    const float* f = hsF + (size_t)idx * 64;
    const float* r = hsR + (size_t)idx * 64;
    float p0 = prib[0], p1 = prib[1], q0 = encb[0], q1 = encb[1];
    #pragma unroll
    for (int k4 = 0; k4 < 16; ++k4) {
        const float4 fv = *(const float4*)(f + k4 * 4);
        const float4 rv = *(const float4*)(r + k4 * 4);
        p0 += dot4(fv, *(const float4*)(priW + k4 * 4));
        p1 += dot4(fv, *(const float4*)(priW + 64 + k4 * 4));
        q0 += dot4(fv, *(const float4*)(encW + k4 * 4))
            + dot4(rv, *(const float4*)(encW + 64 + k4 * 4));
        q1 += dot4(fv, *(const float4*)(encW + 128 + k4 * 4))
            + dot4(rv, *(const float4*)(encW + 192 + k4 * 4));
    }
    float4 o; o.x = p0; o.y = p1; o.z = q0; o.w = q1;
    *(float4*)(out + (size_t)idx * 4) = o;
}

extern "C" void kernel_launch(void* const* d_in, const int* in_sizes, int n_in,
                              void* d_out, int out_size, void* d_ws, size_t ws_size,
                              hipStream_t stream)
{
    const float* x    = (const float*)d_in[0];
    const int*   send = (const int*)d_in[2];
    const int*   recv = (const int*)d_in[3];
    const float* m1W1 = (const float*)d_in[4];  const float* m1b1 = (const float*)d_in[5];
    const float* m1W2 = (const float*)d_in[6];  const float* m1b2 = (const float*)d_in[7];
    const float* m2W1 = (const float*)d_in[8];  const float* m2b1 = (const float*)d_in[9];
    const float* m2W2 = (const float*)d_in[10]; const float* m2b2 = (const float*)d_in[11];
    const float* m3W1 = (const float*)d_in[12]; const float* m3b1 = (const float*)d_in[13];
    const float* m3W2 = (const float*)d_in[14]; const float* m3b2 = (const float*)d_in[15];
    const float* m4W1 = (const float*)d_in[16]; const float* m4b1 = (const float*)d_in[17];
    const float* m4W2 = (const float*)d_in[18]; const float* m4b2 = (const float*)d_in[19];
    const float* fWih = (const float*)d_in[20]; const float* fWhh = (const float*)d_in[21];
    const float* fbih = (const float*)d_in[22]; const float* fbhh = (const float*)d_in[23];
    const float* rWih = (const float*)d_in[24]; const float* rWhh = (const float*)d_in[25];
    const float* rbih = (const float*)d_in[26]; const float* rbhh = (const float*)d_in[27];
    const float* encW = (const float*)d_in[28]; const float* encb = (const float*)d_in[29];
    const float* priW = (const float*)d_in[30]; const float* prib = (const float*)d_in[31];

    const size_t SZN  = (size_t)TN_ * H_;
    const size_t SZE  = (size_t)TE_ * H_;
    float* n_agg = (float*)d_ws;
    float* m3t   = n_agg + SZN;
    us* h16      = (us*)(m3t + SZN);
    us* n3       = h16 + SZN;
    us* w2aH = n3  + SZN;          us* w2aL = w2aH + 256*512;
    us* w2bH = w2aL + 256*512;     us* w2bL = w2bH + 256*256;
    us* w4aH = w2bL + 256*256;     us* w4aL = w4aH + 256*768;
    us* w4bH = w4aL + 256*768;     us* w4bL = w4bH + 256*256;
    us* wfiH = w4bL + 256*256;     us* wfiL = wfiH + 256*256;
    us* wriH = wfiL + 256*256;     us* wriL = wriH + 256*256;
    us* whfH = wriL + 256*256;     us* whfL = whfH + 256*64;
    us* whrH = whfL + 256*64;      us* whrL = whrH + 256*64;
    us* bufA16 = whrL + 256*64;
    us* bufB16 = bufA16 + SZE;
    us* bufC16 = bufB16 + SZE;
    float* hsF = (float*)bufC16;
    float* hsR = hsF + (size_t)TE_ * R_;
    const size_t needed = ((size_t)(bufC16 + SZE) - (size_t)d_ws);
    if (ws_size < needed) return;

    const dim3 gMF(TE_ / 128, 2), gMF4(TE_ / 128, 4), gN(TN_ / 64, 4);
    const us* z = nullptr; const float* zf = nullptr; us* zo = nullptr;

    wsplit_all<<<2432, 256, 0, stream>>>(m2W1, w2aH, w2aL, m2W2, w2bH, w2bL,
                                         m4W1, w4aH, w4aL, m4W2, w4bH, w4bL,
                                         fWih, wfiH, wfiL, rWih, wriH, wriL,
                                         fWhh, whfH, whfL, rWhh, whrH, whrL);

    mlp1_kernel<<<TN_ / 8, 256, 0, stream>>>(x, m1W1, m1b1, m1W2, m1b2, h16);
    gemm_mfma<1, true><<<gMF, 256, 0, stream>>>(h16, h16, nullptr, w2aH, w2aL, m2b1, nullptr, send, recv, bufA16, 512, z, z, zf, zf, zo);
    gemm_mfma<0, true><<<gMF, 256, 0, stream>>>(bufA16, nullptr, nullptr, w2bH, w2bL, m2b2, nullptr, send, recv, bufB16, 256, z, z, zf, zf, zo);
    aggregate_kernel<<<TN_, 256, 0, stream>>>(bufB16, recv, n_agg);
    gemm_nt<true, float, float><<<gN, 256, 0, stream>>>(n_agg, m3W1, m3b1, m3t, TN_, 256);
    gemm_nt<true, float, us><<<gN, 256, 0, stream>>>(m3t, m3W2, m3b2, n3, TN_, 256);
    gemm_mfma<2, true><<<gMF, 256, 0, stream>>>(n3, n3, bufB16, w4aH, w4aL, m4b1, nullptr, send, recv, bufA16, 768, z, z, zf, zf, zo);
    gemm_mfma<0, true><<<gMF, 256, 0, stream>>>(bufA16, nullptr, nullptr, w4bH, w4bL, m4b2, nullptr, send, recv, bufC16, 256, z, z, zf, zf, zo);
    // merged fwd+rev gate GEMMs: by 0-1 -> fwd->bufA16, by 2-3 -> rev->bufB16
    gemm_mfma<0, false><<<gMF4, 256, 0, stream>>>(bufC16, nullptr, nullptr, wfiH, wfiL, fbih, fbhh, send, recv, bufA16, 256,
                                                  wriH, wriL, rbih, rbhh, bufB16);
    lstm_mfma<<<2 * ((E_ + 15) / 16), 256, 0, stream>>>(bufA16, bufB16, whfH, whfL, whrH, whrL, hsF, hsR);
    out_kernel<<<TE_ / 256, 256, 0, stream>>>(hsF, hsR, priW, prib, encW, encb, (float*)d_out);
}

// Round 10
// 604.299 us; speedup vs baseline: 3.6571x; 1.1431x over previous
//
#include <hip/hip_runtime.h>
#include <math.h>

#define T_ 64
#define N_ 40
#define D_ 4
#define H_ 256
#define R_ 64
#define E_ 1560
#define TE_ (T_*E_)
#define TN_ (T_*N_)

typedef unsigned short us;
typedef short short8 __attribute__((ext_vector_type(8)));
typedef float f32x4 __attribute__((ext_vector_type(4)));

__device__ __forceinline__ float elu_f(float x){ return x > 0.f ? x : (__expf(x) - 1.f); }
__device__ __forceinline__ float sig_f(float x){ return 1.f/(1.f+__expf(-x)); }
__device__ __forceinline__ float tanh_f(float x){ return 2.f/(1.f+__expf(-2.f*x)) - 1.f; }
__device__ __forceinline__ float dot4(float4 a, float4 b){ return a.x*b.x + a.y*b.y + a.z*b.z + a.w*b.w; }

__device__ __forceinline__ float bf2f(us u){ return __uint_as_float(((unsigned int)u) << 16); }
__device__ __forceinline__ us f2bf(float f){
    unsigned int u = __float_as_uint(f);
    u += 0x7FFFu + ((u >> 16) & 1u);
    return (us)(u >> 16);
}
__device__ __forceinline__ float4 ld4f(const float* p){ return *(const float4*)p; }
__device__ __forceinline__ float4 ld4f(const us* p){
    ushort4 v = *(const ushort4*)p;
    return make_float4(bf2f(v.x), bf2f(v.y), bf2f(v.z), bf2f(v.w));
}
__device__ __forceinline__ void st4f(float* p, float4 v){ *(float4*)p = v; }
__device__ __forceinline__ void st4f(us* p, float4 v){
    ushort4 o; o.x = f2bf(v.x); o.y = f2bf(v.y); o.z = f2bf(v.z); o.w = f2bf(v.w);
    *(ushort4*)p = o;
}

__device__ __forceinline__ void gld16(void* lds, const void* g){
    __builtin_amdgcn_global_load_lds((const __attribute__((address_space(1))) unsigned int*)g,
                                     (__attribute__((address_space(3))) unsigned int*)lds,
                                     16, 0, 0);
}

__device__ __forceinline__ void wsplit1(const float* W, us* hi, us* lo, int i){
    const float w = W[i];
    const us h = f2bf(w);
    hi[i] = h;
    lo[i] = f2bf(w - bf2f(h));
}

__global__ __launch_bounds__(256)
void wsplit_all(const float* __restrict__ s0, us* h0, us* l0,
                const float* __restrict__ s1, us* h1, us* l1,
                const float* __restrict__ s2, us* h2, us* l2,
                const float* __restrict__ s3, us* h3, us* l3,
                const float* __restrict__ s4, us* h4, us* l4,
                const float* __restrict__ s5, us* h5, us* l5,
                const float* __restrict__ s6, us* h6, us* l6,
                const float* __restrict__ s7, us* h7, us* l7)
{
    int i = blockIdx.x * 256 + threadIdx.x;
    if (i < 131072) { wsplit1(s0, h0, l0, i); return; } i -= 131072;
    if (i <  65536) { wsplit1(s1, h1, l1, i); return; } i -=  65536;
    if (i < 196608) { wsplit1(s2, h2, l2, i); return; } i -= 196608;
    if (i <  65536) { wsplit1(s3, h3, l3, i); return; } i -=  65536;
    if (i <  65536) { wsplit1(s4, h4, l4, i); return; } i -=  65536;
    if (i <  65536) { wsplit1(s5, h5, l5, i); return; } i -=  65536;
    if (i <  16384) { wsplit1(s6, h6, l6, i); return; } i -=  16384;
    wsplit1(s7, h7, l7, i);
}

__global__ __launch_bounds__(256)
void mlp1_kernel(const float* __restrict__ x,
                 const float* __restrict__ W1, const float* __restrict__ b1,
                 const float* __restrict__ W2, const float* __restrict__ b2,
                 us* __restrict__ hout)
{
    __shared__ float xs[8][4];
    __shared__ float h1[8][256];
    const int tid = threadIdx.x;
    const int r0  = blockIdx.x * 8;

    if (tid < 32) xs[tid >> 2][tid & 3] = x[r0 * 4 + tid];
    __syncthreads();

    const float4 w1 = *(const float4*)&W1[tid * 4];
    const float bb1 = b1[tid];
    #pragma unroll
    for (int row = 0; row < 8; ++row) {
        float v = bb1 + xs[row][0]*w1.x + xs[row][1]*w1.y + xs[row][2]*w1.z + xs[row][3]*w1.w;
        h1[row][tid] = elu_f(v);
    }
    __syncthreads();

    float acc[8];
    const float bb2 = b2[tid];
    #pragma unroll
    for (int row = 0; row < 8; ++row) acc[row] = bb2;
    const float* w2row = W2 + (size_t)tid * 256;
    for (int k4 = 0; k4 < 64; ++k4) {
        const float4 w = *(const float4*)&w2row[k4 * 4];
        #pragma unroll
        for (int row = 0; row < 8; ++row) {
            const float4 hh = *(const float4*)&h1[row][k4 * 4];
            acc[row] += dot4(hh, w);
        }
    }
    #pragma unroll
    for (int row = 0; row < 8; ++row)
        hout[(size_t)(r0 + row) * 256 + tid] = f2bf(elu_f(acc[row]));
}

// ---------------------------------------------------------------------------
// MFMA NT GEMM, double-buffered, coalesced staging (4 lanes / row, 64B lines).
// DUAL (MODE 0): blockIdx.y in {2,3} uses second weight/bias/output set.
// ---------------------------------------------------------------------------
template<int MODE, bool DOELU>
__global__ __launch_bounds__(256)
void gemm_mfma(const us* __restrict__ A, const us* __restrict__ A2, const us* __restrict__ A3,
               const us* __restrict__ Whi, const us* __restrict__ Wlo,
               const float* __restrict__ bias1, const float* __restrict__ bias2,
               const int* __restrict__ send, const int* __restrict__ recv,
               us* __restrict__ C, int Kdim,
               const us* __restrict__ Whi2, const us* __restrict__ Wlo2,
               const float* __restrict__ bias1b, const float* __restrict__ bias2b,
               us* __restrict__ C2)
{
    __shared__ char smem[49152];

    const int tid  = threadIdx.x;
    const int lane = tid & 63;
    const int w    = tid >> 6;
    const int ml   = lane & 15;
    const int q    = lane >> 4;
    const int bx   = blockIdx.x;
    int by         = blockIdx.y;
    const int eh   = w >> 1;
    const int fh   = w & 1;

    if (MODE == 0 && C2 != nullptr && by >= 2) {
        Whi = Whi2; Wlo = Wlo2; bias1 = bias1b; bias2 = bias2b; C = C2; by -= 2;
    }

    const int srow0 = w * 32 + (lane >> 2);
    const int srow1 = srow0 + 16;
    const int cofs  = (lane & 3) * 8;

    const int gr0 = bx * 128 + srow0, gr1 = bx * 128 + srow1;
    const us *pA0a=nullptr,*pA1a=nullptr,*pA2a=nullptr;
    const us *pA0b=nullptr,*pA1b=nullptr,*pA2b=nullptr;
    if (MODE == 0) {
        pA0a = A + (size_t)gr0 * Kdim;
        pA0b = A + (size_t)gr1 * Kdim;
    } else {
        const int t0 = gr0 / E_, e0 = gr0 - t0 * E_;
        const int t1 = gr1 / E_, e1 = gr1 - t1 * E_;
        pA0a = A  + ((size_t)(t0 * N_ + send[e0])) * H_;
        pA1a = A2 + ((size_t)(t0 * N_ + recv[e0])) * H_;
        pA0b = A  + ((size_t)(t1 * N_ + send[e1])) * H_;
        pA1b = A2 + ((size_t)(t1 * N_ + recv[e1])) * H_;
        if (MODE == 2) { pA2a = A3 + (size_t)gr0 * H_; pA2b = A3 + (size_t)gr1 * H_; }
    }
    const us* pWh0 = Whi + (size_t)(by * 128 + srow0) * Kdim;
    const us* pWh1 = Whi + (size_t)(by * 128 + srow1) * Kdim;
    const us* pWl0 = Wlo + (size_t)(by * 128 + srow0) * Kdim;
    const us* pWl1 = Wlo + (size_t)(by * 128 + srow1) * Kdim;

    f32x4 acc[4][4];
    #pragma unroll
    for (int i = 0; i < 4; ++i)
        #pragma unroll
        for (int j = 0; j < 4; ++j)
            acc[i][j] = (f32x4){0.f, 0.f, 0.f, 0.f};

    auto stage = [&](int k0, char* base) {
        const us *sa, *sb;
        if (MODE == 0) { sa = pA0a + k0; sb = pA0b + k0; }
        else if (MODE == 1) {
            sa = (k0 < 256) ? pA0a + k0 : pA1a + (k0 - 256);
            sb = (k0 < 256) ? pA0b + k0 : pA1b + (k0 - 256);
        } else {
            sa = (k0 < 256) ? pA0a + k0 : (k0 < 512) ? pA1a + (k0 - 256) : pA2a + (k0 - 512);
            sb = (k0 < 256) ? pA0b + k0 : (k0 < 512) ? pA1b + (k0 - 256) : pA2b + (k0 - 512);
        }
        gld16(base + w * 2048,                sa + cofs);
        gld16(base + w * 2048 + 1024,         sb + cofs);
        gld16(base + 8192  + w * 2048,        pWh0 + k0 + cofs);
        gld16(base + 8192  + w * 2048 + 1024, pWh1 + k0 + cofs);
        gld16(base + 16384 + w * 2048,        pWl0 + k0 + cofs);
        gld16(base + 16384 + w * 2048 + 1024, pWl1 + k0 + cofs);
    };

    stage(0, smem);
    const int nk = Kdim >> 5;
    for (int k = 0; k < nk; ++k) {
        char* cur = smem + (k & 1) * 24576;
        char* nxt = smem + ((k + 1) & 1) * 24576;
        __builtin_amdgcn_s_barrier();
        if (k + 1 < nk) {
            stage((k + 1) * 32, nxt);
            __builtin_amdgcn_s_waitcnt(0x3F76);  // vmcnt(6)
        } else {
            __builtin_amdgcn_s_waitcnt(0x3F70);  // vmcnt(0)
        }
        __builtin_amdgcn_s_barrier();

        short8 wh[4], wl[4], ef[4];
        #pragma unroll
        for (int mt = 0; mt < 4; ++mt) {
            const int fr = fh * 64 + mt * 16 + ml;
            wh[mt] = *(const short8*)(cur + 8192  + fr * 64 + q * 16);
            wl[mt] = *(const short8*)(cur + 16384 + fr * 64 + q * 16);
        }
        #pragma unroll
        for (int nt = 0; nt < 4; ++nt) {
            const int er = eh * 64 + nt * 16 + ml;
            ef[nt] = *(const short8*)(cur + er * 64 + q * 16);
        }
        #pragma unroll
        for (int mt = 0; mt < 4; ++mt)
            #pragma unroll
            for (int nt = 0; nt < 4; ++nt) {
                acc[mt][nt] = __builtin_amdgcn_mfma_f32_16x16x32_bf16(wh[mt], ef[nt], acc[mt][nt], 0, 0, 0);
                acc[mt][nt] = __builtin_amdgcn_mfma_f32_16x16x32_bf16(wl[mt], ef[nt], acc[mt][nt], 0, 0, 0);
            }
    }

    #pragma unroll
    for (int mt = 0; mt < 4; ++mt) {
        const int colb = by * 128 + fh * 64 + mt * 16 + q * 4;
        float4 bb = *(const float4*)(bias1 + colb);
        if (bias2) {
            const float4 b2 = *(const float4*)(bias2 + colb);
            bb.x += b2.x; bb.y += b2.y; bb.z += b2.z; bb.w += b2.w;
        }
        #pragma unroll
        for (int nt = 0; nt < 4; ++nt) {
            const int row = bx * 128 + eh * 64 + nt * 16 + ml;
            float4 v;
            v.x = acc[mt][nt][0] + bb.x; v.y = acc[mt][nt][1] + bb.y;
            v.z = acc[mt][nt][2] + bb.z; v.w = acc[mt][nt][3] + bb.w;
            if (DOELU) { v.x = elu_f(v.x); v.y = elu_f(v.y); v.z = elu_f(v.z); v.w = elu_f(v.w); }
            ushort4 o; o.x = f2bf(v.x); o.y = f2bf(v.y); o.z = f2bf(v.z); o.w = f2bf(v.w);
            *(ushort4*)(C + (size_t)row * 256 + colb) = o;
        }
    }
}

template<bool DOELU, typename TA, typename TC>
__global__ __launch_bounds__(256)
void gemm_nt(const TA* __restrict__ A, const float* __restrict__ W,
             const float* __restrict__ bias1,
             TC* __restrict__ C, int M, int Kdim)
{
    __shared__ float As[16][64];
    __shared__ float Ws[16][64];

    const int tid = threadIdx.x;
    const int am  = tid >> 2;
    const int ak  = (tid & 3) * 4;
    const int gm  = blockIdx.x * 64 + am;

    const TA* aptr0 = A + (size_t)gm * Kdim;
    const float* wptr = W + (size_t)(blockIdx.y * 64 + am) * Kdim;

    const int tx = tid & 15, ty = tid >> 4;
    float acc[4][4] = {};

    for (int k0 = 0; k0 < Kdim; k0 += 16) {
        const float4 a4 = ld4f(aptr0 + k0 + ak);
        const float4 w4 = *(const float4*)(wptr + k0 + (tid & 3) * 4);

        __syncthreads();
        As[ak+0][am] = a4.x; As[ak+1][am] = a4.y; As[ak+2][am] = a4.z; As[ak+3][am] = a4.w;
        const int wk = (tid & 3) * 4;
        Ws[wk+0][am] = w4.x; Ws[wk+1][am] = w4.y; Ws[wk+2][am] = w4.z; Ws[wk+3][am] = w4.w;
        __syncthreads();

        #pragma unroll
        for (int kq = 0; kq < 16; ++kq) {
            const float4 av = *(const float4*)&As[kq][ty * 4];
            const float4 wv = *(const float4*)&Ws[kq][tx * 4];
            const float a_[4] = {av.x, av.y, av.z, av.w};
            const float w_[4] = {wv.x, wv.y, wv.z, wv.w};
            #pragma unroll
            for (int i = 0; i < 4; ++i)
                #pragma unroll
                for (int j = 0; j < 4; ++j)
                    acc[i][j] += a_[i] * w_[j];
        }
    }

    const int gn = blockIdx.y * 64 + tx * 4;
    const float4 bb = *(const float4*)&bias1[gn];
    #pragma unroll
    for (int i = 0; i < 4; ++i) {
        const int row = blockIdx.x * 64 + ty * 4 + i;
        float4 o;
        o.x = acc[i][0] + bb.x; o.y = acc[i][1] + bb.y;
        o.z = acc[i][2] + bb.z; o.w = acc[i][3] + bb.w;
        if (DOELU) { o.x = elu_f(o.x); o.y = elu_f(o.y); o.z = elu_f(o.z); o.w = elu_f(o.w); }
        st4f(C + (size_t)row * 256 + gn, o);
    }
}

// ---------------------------------------------------------------------------
// edge2node aggregate, analytic edge list (static fully-connected graph):
// edge (s -> j) has index e = s*39 + (j < s ? j : j-1). Loop over s ascending
// == old loop over e ascending for recv==j -> bit-identical summation order.
// ---------------------------------------------------------------------------
__global__ __launch_bounds__(256)
void aggregate_kernel(const us* __restrict__ eSkip, const int* __restrict__ recv,
                      float* __restrict__ nAgg)
{
    const int t = blockIdx.x / N_;
    const int j = blockIdx.x - t * N_;
    const int c = threadIdx.x;
    const us* basep = eSkip + (size_t)t * E_ * H_ + c;
    float acc = 0.f;
    #pragma unroll
    for (int s = 0; s < N_; ++s) {
        if (s == j) continue;
        const int e = s * (N_ - 1) + (j < s ? j : j - 1);
        acc += bf2f(basep[(size_t)e * H_]);
    }
    nAgg[(size_t)blockIdx.x * H_ + c] = acc;
}

// LSTM recurrence: MFMA recurrent GEMM (unchanged).
__global__ __launch_bounds__(256)
void lstm_mfma(const us* __restrict__ Gf, const us* __restrict__ Gr,
               const us* __restrict__ fWhhH, const us* __restrict__ fWhhL,
               const us* __restrict__ rWhhH, const us* __restrict__ rWhhL,
               float* __restrict__ hsF, float* __restrict__ hsR)
{
    const int NBD = (E_ + 15) / 16;
    const bool revd = (int)blockIdx.x >= NBD;
    const int blk = revd ? (int)blockIdx.x - NBD : (int)blockIdx.x;
    const int e0 = blk * 16;
    const us* G  = revd ? Gr : Gf;
    const us* WH = revd ? rWhhH : fWhhH;
    const us* WL = revd ? rWhhL : fWhhL;
    float* hs    = revd ? hsR : hsF;

    const int tid  = threadIdx.x;
    const int lane = tid & 63;
    const int w    = tid >> 6;
    const int ml   = lane & 15;
    const int q    = lane >> 4;

    __shared__ float g_s[4][16][68];
    __shared__ us hHi[16][72];
    __shared__ us hLo[16][72];

    short8 wfh[4][2], wfl[4][2];
    #pragma unroll
    for (int mt = 0; mt < 4; ++mt) {
        const int row = w * 64 + mt * 16 + ml;
        #pragma unroll
        for (int ks = 0; ks < 2; ++ks) {
            wfh[mt][ks] = *(const short8*)(WH + (size_t)row * 64 + ks * 32 + q * 8);
            wfl[mt][ks] = *(const short8*)(WL + (size_t)row * 64 + ks * 32 + q * 8);
        }
    }

    for (int i = tid; i < 16 * 72; i += 256) { ((us*)hHi)[i] = 0; ((us*)hLo)[i] = 0; }

    const int ped = tid >> 4;
    const int prr = (tid & 15) * 4;
    float4 cst = make_float4(0.f, 0.f, 0.f, 0.f);

    const int eMF = min(e0 + ml, E_ - 1);
    const int gb  = w * 64 + q * 4;

    ushort4 gcur[4], gnxt[4];
    {
        const int tt0 = revd ? (T_ - 1) : 0;
        const us* gp = G + ((size_t)tt0 * E_ + eMF) * 256 + gb;
        #pragma unroll
        for (int mt = 0; mt < 4; ++mt) gcur[mt] = *(const ushort4*)(gp + mt * 16);
    }
    __syncthreads();

    for (int s = 0; s < T_; ++s) {
        const int tt = revd ? (T_ - 1 - s) : s;
        {
            const int sn = (s + 1 < T_) ? s + 1 : s;
            const int tn = revd ? (T_ - 1 - sn) : sn;
            const us* gp = G + ((size_t)tn * E_ + eMF) * 256 + gb;
            #pragma unroll
            for (int mt = 0; mt < 4; ++mt) gnxt[mt] = *(const ushort4*)(gp + mt * 16);
        }
        short8 bh[2], bl[2];
        #pragma unroll
        for (int ks = 0; ks < 2; ++ks) {
            bh[ks] = *(const short8*)(&hHi[ml][ks * 32 + q * 8]);
            bl[ks] = *(const short8*)(&hLo[ml][ks * 32 + q * 8]);
        }
        #pragma unroll
        for (int mt = 0; mt < 4; ++mt) {
            f32x4 acc;
            acc[0] = bf2f(gcur[mt].x); acc[1] = bf2f(gcur[mt].y);
            acc[2] = bf2f(gcur[mt].z); acc[3] = bf2f(gcur[mt].w);
            #pragma unroll
            for (int ks = 0; ks < 2; ++ks) {
                acc = __builtin_amdgcn_mfma_f32_16x16x32_bf16(wfh[mt][ks], bh[ks], acc, 0, 0, 0);
                acc = __builtin_amdgcn_mfma_f32_16x16x32_bf16(wfh[mt][ks], bl[ks], acc, 0, 0, 0);
                acc = __builtin_amdgcn_mfma_f32_16x16x32_bf16(wfl[mt][ks], bh[ks], acc, 0, 0, 0);
            }
            *(f32x4*)(&g_s[w][ml][mt * 16 + q * 4]) = acc;
        }
        __syncthreads();
        {
            const float4 gi = *(const float4*)&g_s[0][ped][prr];
            const float4 gf = *(const float4*)&g_s[1][ped][prr];
            const float4 gg = *(const float4*)&g_s[2][ped][prr];
            const float4 go = *(const float4*)&g_s[3][ped][prr];
            float4 hv;
            cst.x = sig_f(gf.x)*cst.x + sig_f(gi.x)*tanh_f(gg.x); hv.x = sig_f(go.x)*tanh_f(cst.x);
            cst.y = sig_f(gf.y)*cst.y + sig_f(gi.y)*tanh_f(gg.y); hv.y = sig_f(go.y)*tanh_f(cst.y);
            cst.z = sig_f(gf.z)*cst.z + sig_f(gi.z)*tanh_f(gg.z); hv.z = sig_f(go.z)*tanh_f(cst.z);
            cst.w = sig_f(gf.w)*cst.w + sig_f(gi.w)*tanh_f(gg.w); hv.w = sig_f(go.w)*tanh_f(cst.w);
            ushort4 hh4, hl4;
            hh4.x = f2bf(hv.x); hl4.x = f2bf(hv.x - bf2f(hh4.x));
            hh4.y = f2bf(hv.y); hl4.y = f2bf(hv.y - bf2f(hh4.y));
            hh4.z = f2bf(hv.z); hl4.z = f2bf(hv.z - bf2f(hh4.z));
            hh4.w = f2bf(hv.w); hl4.w = f2bf(hv.w - bf2f(hh4.w));
            *(ushort4*)(&hHi[ped][prr]) = hh4;
            *(ushort4*)(&hLo[ped][prr]) = hl4;
            if (e0 + ped < E_)
                *(float4*)(&hs[((size_t)tt * E_ + e0 + ped) * 64 + prr]) = hv;
        }
        __syncthreads();
        #pragma unroll
        for (int mt = 0; mt < 4; ++mt) gcur[mt] = gnxt[mt];
    }
}

__global__ __launch_bounds__(256)
void out_kernel(const float* __restrict__ hsF, const float* __restrict__ hsR,
                const float* __restrict__ priW, const float* __restrict__ prib,
                const float* __restrict__ encW, const float* __restrict__ encb,
                float* __restrict__ out)
{
    const int idx = blockIdx.x * 256 + threadIdx.x;
    const float* f = hsF + (size_t)idx * 64;
    const float* r = hsR + (size_t)idx * 64;
    float p0 = prib[0], p1 = prib[1], q0 = encb[0], q1 = encb[1];
    #pragma unroll
    for (int k4 = 0; k4 < 16; ++k4) {
        const float4 fv = *(const float4*)(f + k4 * 4);
        const float4 rv = *(const float4*)(r + k4 * 4);
        p0 += dot4(fv, *(const float4*)(priW + k4 * 4));
        p1 += dot4(fv, *(const float4*)(priW + 64 + k4 * 4));
        q0 += dot4(fv, *(const float4*)(encW + k4 * 4))
            + dot4(rv, *(const float4*)(encW + 64 + k4 * 4));
        q1 += dot4(fv, *(const float4*)(encW + 128 + k4 * 4))
            + dot4(rv, *(const float4*)(encW + 192 + k4 * 4));
    }
    float4 o; o.x = p0; o.y = p1; o.z = q0; o.w = q1;
    *(float4*)(out + (size_t)idx * 4) = o;
}

extern "C" void kernel_launch(void* const* d_in, const int* in_sizes, int n_in,
                              void* d_out, int out_size, void* d_ws, size_t ws_size,
                              hipStream_t stream)
{
    const float* x    = (const float*)d_in[0];
    const int*   send = (const int*)d_in[2];
    const int*   recv = (const int*)d_in[3];
    const float* m1W1 = (const float*)d_in[4];  const float* m1b1 = (const float*)d_in[5];
    const float* m1W2 = (const float*)d_in[6];  const float* m1b2 = (const float*)d_in[7];
    const float* m2W1 = (const float*)d_in[8];  const float* m2b1 = (const float*)d_in[9];
    const float* m2W2 = (const float*)d_in[10]; const float* m2b2 = (const float*)d_in[11];
    const float* m3W1 = (const float*)d_in[12]; const float* m3b1 = (const float*)d_in[13];
    const float* m3W2 = (const float*)d_in[14]; const float* m3b2 = (const float*)d_in[15];
    const float* m4W1 = (const float*)d_in[16]; const float* m4b1 = (const float*)d_in[17];
    const float* m4W2 = (const float*)d_in[18]; const float* m4b2 = (const float*)d_in[19];
    const float* fWih = (const float*)d_in[20]; const float* fWhh = (const float*)d_in[21];
    const float* fbih = (const float*)d_in[22]; const float* fbhh = (const float*)d_in[23];
    const float* rWih = (const float*)d_in[24]; const float* rWhh = (const float*)d_in[25];
    const float* rbih = (const float*)d_in[26]; const float* rbhh = (const float*)d_in[27];
    const float* encW = (const float*)d_in[28]; const float* encb = (const float*)d_in[29];
    const float* priW = (const float*)d_in[30]; const float* prib = (const float*)d_in[31];

    const size_t SZN  = (size_t)TN_ * H_;
    const size_t SZE  = (size_t)TE_ * H_;
    float* n_agg = (float*)d_ws;
    float* m3t   = n_agg + SZN;
    us* h16      = (us*)(m3t + SZN);
    us* n3       = h16 + SZN;
    us* w2aH = n3  + SZN;          us* w2aL = w2aH + 256*512;
    us* w2bH = w2aL + 256*512;     us* w2bL = w2bH + 256*256;
    us* w4aH = w2bL + 256*256;     us* w4aL = w4aH + 256*768;
    us* w4bH = w4aL + 256*768;     us* w4bL = w4bH + 256*256;
    us* wfiH = w4bL + 256*256;     us* wfiL = wfiH + 256*256;
    us* wriH = wfiL + 256*256;     us* wriL = wriH + 256*256;
    us* whfH = wriL + 256*256;     us* whfL = whfH + 256*64;
    us* whrH = whfL + 256*64;      us* whrL = whrH + 256*64;
    us* bufA16 = whrL + 256*64;
    us* bufB16 = bufA16 + SZE;
    us* bufC16 = bufB16 + SZE;
    float* hsF = (float*)bufC16;
    float* hsR = hsF + (size_t)TE_ * R_;
    const size_t needed = ((size_t)(bufC16 + SZE) - (size_t)d_ws);
    if (ws_size < needed) return;

    const dim3 gMF(TE_ / 128, 2), gMF4(TE_ / 128, 4), gN(TN_ / 64, 4);
    const us* z = nullptr; const float* zf = nullptr; us* zo = nullptr;

    wsplit_all<<<2432, 256, 0, stream>>>(m2W1, w2aH, w2aL, m2W2, w2bH, w2bL,
                                         m4W1, w4aH, w4aL, m4W2, w4bH, w4bL,
                                         fWih, wfiH, wfiL, rWih, wriH, wriL,
                                         fWhh, whfH, whfL, rWhh, whrH, whrL);

    mlp1_kernel<<<TN_ / 8, 256, 0, stream>>>(x, m1W1, m1b1, m1W2, m1b2, h16);
    gemm_mfma<1, true><<<gMF, 256, 0, stream>>>(h16, h16, nullptr, w2aH, w2aL, m2b1, nullptr, send, recv, bufA16, 512, z, z, zf, zf, zo);
    gemm_mfma<0, true><<<gMF, 256, 0, stream>>>(bufA16, nullptr, nullptr, w2bH, w2bL, m2b2, nullptr, send, recv, bufB16, 256, z, z, zf, zf, zo);
    aggregate_kernel<<<TN_, 256, 0, stream>>>(bufB16, recv, n_agg);
    gemm_nt<true, float, float><<<gN, 256, 0, stream>>>(n_agg, m3W1, m3b1, m3t, TN_, 256);
    gemm_nt<true, float, us><<<gN, 256, 0, stream>>>(m3t, m3W2, m3b2, n3, TN_, 256);
    gemm_mfma<2, true><<<gMF, 256, 0, stream>>>(n3, n3, bufB16, w4aH, w4aL, m4b1, nullptr, send, recv, bufA16, 768, z, z, zf, zf, zo);
    gemm_mfma<0, true><<<gMF, 256, 0, stream>>>(bufA16, nullptr, nullptr, w4bH, w4bL, m4b2, nullptr, send, recv, bufC16, 256, z, z, zf, zf, zo);
    gemm_mfma<0, false><<<gMF4, 256, 0, stream>>>(bufC16, nullptr, nullptr, wfiH, wfiL, fbih, fbhh, send, recv, bufA16, 256,
                                                  wriH, wriL, rbih, rbhh, bufB16);
    lstm_mfma<<<2 * ((E_ + 15) / 16), 256, 0, stream>>>(bufA16, bufB16, whfH, whfL, whrH, whrL, hsF, hsR);
    out_kernel<<<TE_ / 256, 256, 0, stream>>>(hsF, hsR, priW, prib, encW, encb, (float*)d_out);
}